// Round 1
// baseline (3825.675 us; speedup 1.0000x reference)
//
#include <hip/hip_runtime.h>
#include <math.h>

// ---------------------------------------------------------------------------
// MCKRL: 3 live channels x 4 relations RGCN (2 layers) + semantic attention.
// Channel 1 of 4 is dead code (z stacks channels 0,2,3 only) -> skipped.
// Strategy: CSR per (channel,relation) graph built on-device each call
// (harness re-poisons d_ws), transform-first GEMM (in_f > out_f), fused
// atomic-free two-relation gather + bias + relu.
// All fp32 this round (correctness baseline); GEMM -> bf16 MFMA later.
// ---------------------------------------------------------------------------

#define IN_F  512
#define HID_F 256
#define OUT_F 128
#define NG    12   // 3 channels x 4 relations

__device__ __forceinline__ int chan_of(int ci) { return ci == 0 ? 0 : ci + 1; } // {0,2,3}

// ---------------- degree histograms ----------------
__global__ void k_degrees(const int* __restrict__ src, const int* __restrict__ dst,
                          int* __restrict__ deg_out, int* __restrict__ deg_in,
                          int N, int E) {
    int g = blockIdx.y;
    int e = blockIdx.x * blockDim.x + threadIdx.x;
    if (e >= E) return;
    int ci = g >> 2, r = g & 3;
    int c = chan_of(ci);
    size_t base = (size_t)(c * 4 + r) * E;
    int s = src[base + e], d = dst[base + e];
    atomicAdd(&deg_out[(size_t)g * N + s], 1);
    atomicAdd(&deg_in [(size_t)g * N + d], 1);
}

// ---------------- deg^{-1/2} ----------------
__global__ void k_rs(const int* __restrict__ deg_out, const int* __restrict__ deg_in,
                     float* __restrict__ rs_out, float* __restrict__ rs_in, int total) {
    int i = blockIdx.x * blockDim.x + threadIdx.x;
    if (i >= total) return;
    rs_out[i] = rsqrtf(fmaxf((float)deg_out[i], 1.0f));
    rs_in[i]  = rsqrtf(fmaxf((float)deg_in[i],  1.0f));
}

// ---------------- exclusive scan of deg_in -> row_ptr (+cursor copy) ------
__global__ __launch_bounds__(1024) void k_scan(const int* __restrict__ deg_in,
                                               int* __restrict__ row_ptr,
                                               int* __restrict__ cursor, int N) {
    int g = blockIdx.x;
    const int* deg = deg_in + (size_t)g * N;
    int* rp  = row_ptr + (size_t)g * (N + 1);
    int* cur = cursor  + (size_t)g * N;
    __shared__ int buf[1024];
    __shared__ int s_run;
    int tid = threadIdx.x;
    if (tid == 0) s_run = 0;
    __syncthreads();
    for (int base = 0; base < N; base += 1024) {
        int i = base + tid;
        int v = (i < N) ? deg[i] : 0;
        buf[tid] = v;
        __syncthreads();
        for (int off = 1; off < 1024; off <<= 1) {
            int t = (tid >= off) ? buf[tid - off] : 0;
            __syncthreads();
            buf[tid] += t;
            __syncthreads();
        }
        int run = s_run;
        int ex = run + buf[tid] - v;
        if (i < N) { rp[i] = ex; cur[i] = ex; }
        __syncthreads();
        if (tid == 0) s_run = run + buf[1023];
        __syncthreads();
    }
    if (tid == 0) rp[N] = s_run;
}

// ---------------- CSR fill (sorted-by-dst edge list, col = src id) --------
__global__ void k_fill(const int* __restrict__ src, const int* __restrict__ dst,
                       int* __restrict__ cursor, int* __restrict__ col,
                       int N, int E) {
    int g = blockIdx.y;
    int e = blockIdx.x * blockDim.x + threadIdx.x;
    if (e >= E) return;
    int ci = g >> 2, r = g & 3;
    int c = chan_of(ci);
    size_t base = (size_t)(c * 4 + r) * E;
    int s = src[base + e], d = dst[base + e];
    int pos = atomicAdd(&cursor[(size_t)g * N + d], 1);
    col[(size_t)g * E + pos] = s;
}

// ---------------- fp32 tiled GEMM: C[M,Nn] = A[M,K] @ B[K,Nn] -------------
// 64x64 tile, BK=16, 256 threads, 4x4 micro-tile per thread.
__global__ __launch_bounds__(256) void k_gemm(const float* __restrict__ A,
                                              const float* __restrict__ B,
                                              float* __restrict__ C,
                                              int M, int K, int Nn) {
    __shared__ float As[16][64];  // [k][m]
    __shared__ float Bs[16][64];  // [k][n]
    int tid = threadIdx.x;
    int tx = tid & 15, ty = tid >> 4;
    int brow = blockIdx.y * 64, bcol = blockIdx.x * 64;

    float acc[4][4] = {};

    int arow = tid >> 2;            // 0..63
    int ak   = (tid & 3) << 2;      // 0,4,8,12
    int bk   = tid >> 4;            // 0..15
    int bcl  = (tid & 15) << 2;     // 0..60

    int arG = brow + arow; if (arG > M - 1) arG = M - 1;   // clamp; stores guarded
    const float* Ap = A + (size_t)arG * K + ak;
    const float* Bp = B + (size_t)bk * Nn + bcol + bcl;

    for (int k0 = 0; k0 < K; k0 += 16) {
        float4 av = *(const float4*)(Ap + k0);
        float4 bv = *(const float4*)(Bp + (size_t)k0 * Nn);
        __syncthreads();   // protect previous iteration's LDS reads
        As[ak + 0][arow] = av.x;
        As[ak + 1][arow] = av.y;
        As[ak + 2][arow] = av.z;
        As[ak + 3][arow] = av.w;
        *(float4*)&Bs[bk][bcl] = bv;
        __syncthreads();
#pragma unroll
        for (int k = 0; k < 16; ++k) {
            const float4 rav = *(const float4*)&As[k][ty << 2];
            const float4 rbv = *(const float4*)&Bs[k][tx << 2];
            const float ra[4] = {rav.x, rav.y, rav.z, rav.w};
            const float rb[4] = {rbv.x, rbv.y, rbv.z, rbv.w};
#pragma unroll
            for (int ii = 0; ii < 4; ++ii)
#pragma unroll
                for (int jj = 0; jj < 4; ++jj)
                    acc[ii][jj] = fmaf(ra[ii], rb[jj], acc[ii][jj]);
        }
    }
#pragma unroll
    for (int ii = 0; ii < 4; ++ii) {
        int r = brow + (ty << 2) + ii;
        if (r < M) {
            float4 cv = make_float4(acc[ii][0], acc[ii][1], acc[ii][2], acc[ii][3]);
            *(float4*)&C[(size_t)r * Nn + bcol + (tx << 2)] = cv;
        }
    }
}

// ------- fused two-relation gather + norm + bias + relu (no atomics) ------
// out[i*ostride+f] = relu( rs_in_a[i]*sum_{e in a(i)} rs_out_a[s]*Ya[s,f] + ba[f]
//                        + rs_in_b[i]*sum_{e in b(i)} rs_out_b[s]*Yb[s,f] + bb[f] )
__global__ void k_agg(const float* __restrict__ Ya, const float* __restrict__ Yb,
                      const int* __restrict__ row_ptr, const int* __restrict__ col,
                      const float* __restrict__ rs_out, const float* __restrict__ rs_in,
                      int ga, int gb,
                      const float* __restrict__ ba, const float* __restrict__ bb,
                      float* __restrict__ out, int F, int ostride, int N, int E) {
    int i = blockIdx.x;
    int f = threadIdx.x;  // blockDim.x == F
    float acc = ba[f] + bb[f];
    {
        const int* rp = row_ptr + (size_t)ga * (N + 1);
        const int* cg = col + (size_t)ga * E;
        const float* ro = rs_out + (size_t)ga * N;
        int beg = rp[i], end = rp[i + 1];
        float s = 0.0f;
        int sn = (beg < end) ? cg[beg] : 0;
        for (int e = beg; e < end; ++e) {
            int sn1 = (e + 1 < end) ? cg[e + 1] : 0;   // prefetch next edge
            s += ro[sn] * Ya[(size_t)sn * F + f];
            sn = sn1;
        }
        acc += rs_in[(size_t)ga * N + i] * s;
    }
    {
        const int* rp = row_ptr + (size_t)gb * (N + 1);
        const int* cg = col + (size_t)gb * E;
        const float* ro = rs_out + (size_t)gb * N;
        int beg = rp[i], end = rp[i + 1];
        float s = 0.0f;
        int sn = (beg < end) ? cg[beg] : 0;
        for (int e = beg; e < end; ++e) {
            int sn1 = (e + 1 < end) ? cg[e + 1] : 0;
            s += ro[sn] * Yb[(size_t)sn * F + f];
            sn = sn1;
        }
        acc += rs_in[(size_t)gb * N + i] * s;
    }
    out[(size_t)i * ostride + f] = fmaxf(acc, 0.0f);
}

// ---------------- semantic attention: per-node w scores -------------------
// w[side,k,i] = sum_f tanh( (z[i,k,:] @ Wp)[f] + bp[f] ) * q[f]
__global__ __launch_bounds__(128) void k_attn_w(const float* __restrict__ zd,
                                                const float* __restrict__ zp,
                                                const float* __restrict__ Wp,
                                                const float* __restrict__ bp,
                                                const float* __restrict__ q,
                                                float* __restrict__ w_all, int N) {
    int i = blockIdx.x, side = blockIdx.y;
    const float* z = side ? zp : zd;
    int f = threadIdx.x;  // 128
    __shared__ float zl[3][128];
#pragma unroll
    for (int k = 0; k < 3; ++k) zl[k][f] = z[(size_t)i * 384 + k * 128 + f];
    __syncthreads();
    float a0 = bp[f], a1 = bp[f], a2 = bp[f];
    for (int j = 0; j < 128; ++j) {
        float wv = Wp[j * 128 + f];
        a0 = fmaf(zl[0][j], wv, a0);
        a1 = fmaf(zl[1][j], wv, a1);
        a2 = fmaf(zl[2][j], wv, a2);
    }
    float qf = q[f];
    float tv[3] = {tanhf(a0) * qf, tanhf(a1) * qf, tanhf(a2) * qf};
    __shared__ float red[128];
#pragma unroll
    for (int k = 0; k < 3; ++k) {
        __syncthreads();
        red[f] = tv[k];
        __syncthreads();
        for (int off = 64; off > 0; off >>= 1) {
            if (f < off) red[f] += red[f + off];
            __syncthreads();
        }
        if (f == 0) w_all[((size_t)side * 3 + k) * N + i] = red[0];
    }
}

// ---------------- beta: deterministic reduce + softmax --------------------
__global__ __launch_bounds__(256) void k_beta(const float* __restrict__ w_all,
                                              float* __restrict__ beta_ws,
                                              float* __restrict__ beta_out, int N) {
    int side = blockIdx.x;
    int tid = threadIdx.x;
    __shared__ float red[256];
    float sums[3];
    for (int k = 0; k < 3; ++k) {
        float s = 0.0f;
        for (int i = tid; i < N; i += 256) s += w_all[((size_t)side * 3 + k) * N + i];
        red[tid] = s;
        __syncthreads();
        for (int off = 128; off > 0; off >>= 1) {
            if (tid < off) red[tid] += red[tid + off];
            __syncthreads();
        }
        sums[k] = red[0];
        __syncthreads();
    }
    if (tid == 0) {
        float inv = 1.0f / (float)N;
        float m0 = sums[0] * inv, m1 = sums[1] * inv, m2 = sums[2] * inv;
        float mx = fmaxf(m0, fmaxf(m1, m2));
        float e0 = expf(m0 - mx), e1 = expf(m1 - mx), e2 = expf(m2 - mx);
        float denom = e0 + e1 + e2;
        float b0 = e0 / denom, b1 = e1 / denom, b2 = e2 / denom;
        beta_ws[side * 3 + 0] = b0; beta_out[side * 3 + 0] = b0;
        beta_ws[side * 3 + 1] = b1; beta_out[side * 3 + 1] = b1;
        beta_ws[side * 3 + 2] = b2; beta_out[side * 3 + 2] = b2;
    }
}

// ---------------- emb = sum_k beta[k] * z[:,k,:] --------------------------
__global__ __launch_bounds__(128) void k_emb(const float* __restrict__ zd,
                                             const float* __restrict__ zp,
                                             const float* __restrict__ beta_ws,
                                             float* __restrict__ out, int N) {
    int i = blockIdx.x, side = blockIdx.y, f = threadIdx.x;
    const float* z = side ? zp : zd;
    const float* b = beta_ws + side * 3;
    float v = b[0] * z[(size_t)i * 384 + f]
            + b[1] * z[(size_t)i * 384 + 128 + f]
            + b[2] * z[(size_t)i * 384 + 256 + f];
    out[(size_t)side * N * 128 + (size_t)i * 128 + f] = v;
}

// ---------------------------------------------------------------------------
extern "C" void kernel_launch(void* const* d_in, const int* in_sizes, int n_in,
                              void* d_out, int out_size, void* d_ws, size_t ws_size,
                              hipStream_t stream) {
    const float* x_drug = (const float*)d_in[0];
    const float* x_pro  = (const float*)d_in[1];
    const int*   src    = (const int*)d_in[2];
    const int*   dst    = (const int*)d_in[3];
    const float* W1     = (const float*)d_in[4];
    const float* b1     = (const float*)d_in[5];
    const float* W2     = (const float*)d_in[6];
    const float* b2     = (const float*)d_in[7];
    const float* Wp     = (const float*)d_in[8];
    const float* bp     = (const float*)d_in[9];
    const float* q      = (const float*)d_in[10];
    float* out = (float*)d_out;

    const int N = in_sizes[0] / IN_F;      // 30000
    const int E = in_sizes[2] / 16;        // 250000

    // ---- workspace carve-up (256B aligned regions) ----
    size_t off = 0;
    auto alloc = [&](size_t bytes) -> void* {
        void* p = (char*)d_ws + off;
        off += (bytes + 255) & ~(size_t)255;
        return p;
    };
    int*   deg_out = (int*)alloc((size_t)NG * N * 4);
    int*   deg_in  = (int*)alloc((size_t)NG * N * 4);
    int*   row_ptr = (int*)alloc((size_t)NG * (N + 1) * 4);
    int*   cursor  = (int*)alloc((size_t)NG * N * 4);
    int*   col     = (int*)alloc((size_t)NG * E * 4);
    float* rs_out  = (float*)alloc((size_t)NG * N * 4);
    float* rs_in   = (float*)alloc((size_t)NG * N * 4);
    float* H1d     = (float*)alloc((size_t)N * HID_F * 4);
    float* H1p     = (float*)alloc((size_t)N * HID_F * 4);
    float* Ya      = (float*)alloc((size_t)N * HID_F * 4);
    float* Yb      = (float*)alloc((size_t)N * HID_F * 4);
    float* zd      = (float*)alloc((size_t)N * 3 * OUT_F * 4);
    float* zp      = (float*)alloc((size_t)N * 3 * OUT_F * 4);
    float* w_all   = (float*)alloc((size_t)2 * 3 * N * 4);
    float* beta_ws = (float*)alloc(64);
    (void)ws_size; (void)n_in; (void)out_size;

    // ---- zero degree histograms (ws is poisoned each call) ----
    hipMemsetAsync(deg_out, 0, (size_t)NG * N * 4, stream);
    hipMemsetAsync(deg_in,  0, (size_t)NG * N * 4, stream);

    // ---- CSR build ----
    dim3 egrid((E + 255) / 256, NG);
    k_degrees<<<egrid, 256, 0, stream>>>(src, dst, deg_out, deg_in, N, E);
    k_rs<<<(NG * N + 255) / 256, 256, 0, stream>>>(deg_out, deg_in, rs_out, rs_in, NG * N);
    k_scan<<<NG, 1024, 0, stream>>>(deg_in, row_ptr, cursor, N);
    k_fill<<<egrid, 256, 0, stream>>>(src, dst, cursor, col, N, E);

    const int chanv[3] = {0, 2, 3};
    dim3 g1(HID_F / 64, (N + 63) / 64);   // layer-1 GEMM grid (256 cols)
    dim3 g2(OUT_F / 64, (N + 63) / 64);   // layer-2 GEMM grid (128 cols)

    for (int ci = 0; ci < 3; ++ci) {
        int c = chanv[ci];
        // ---- layer 1, drug output: rel 0 (xd->d), rel 2 (xp->d) ----
        k_gemm<<<g1, 256, 0, stream>>>(x_drug, W1 + (size_t)(c * 4 + 0) * IN_F * HID_F, Ya, N, IN_F, HID_F);
        k_gemm<<<g1, 256, 0, stream>>>(x_pro,  W1 + (size_t)(c * 4 + 2) * IN_F * HID_F, Yb, N, IN_F, HID_F);
        k_agg<<<N, HID_F, 0, stream>>>(Ya, Yb, row_ptr, col, rs_out, rs_in,
                                       ci * 4 + 0, ci * 4 + 2,
                                       b1 + (size_t)(c * 4 + 0) * HID_F, b1 + (size_t)(c * 4 + 2) * HID_F,
                                       H1d, HID_F, HID_F, N, E);
        // ---- layer 1, protein output: rel 1 (xd->p), rel 3 (xp->p) ----
        k_gemm<<<g1, 256, 0, stream>>>(x_drug, W1 + (size_t)(c * 4 + 1) * IN_F * HID_F, Ya, N, IN_F, HID_F);
        k_gemm<<<g1, 256, 0, stream>>>(x_pro,  W1 + (size_t)(c * 4 + 3) * IN_F * HID_F, Yb, N, IN_F, HID_F);
        k_agg<<<N, HID_F, 0, stream>>>(Ya, Yb, row_ptr, col, rs_out, rs_in,
                                       ci * 4 + 1, ci * 4 + 3,
                                       b1 + (size_t)(c * 4 + 1) * HID_F, b1 + (size_t)(c * 4 + 3) * HID_F,
                                       H1p, HID_F, HID_F, N, E);
        // ---- layer 2, drug output -> zd[:, ci, :] ----
        k_gemm<<<g2, 256, 0, stream>>>(H1d, W2 + (size_t)(c * 4 + 0) * HID_F * OUT_F, Ya, N, HID_F, OUT_F);
        k_gemm<<<g2, 256, 0, stream>>>(H1p, W2 + (size_t)(c * 4 + 2) * HID_F * OUT_F, Yb, N, HID_F, OUT_F);
        k_agg<<<N, OUT_F, 0, stream>>>(Ya, Yb, row_ptr, col, rs_out, rs_in,
                                       ci * 4 + 0, ci * 4 + 2,
                                       b2 + (size_t)(c * 4 + 0) * OUT_F, b2 + (size_t)(c * 4 + 2) * OUT_F,
                                       zd + (size_t)ci * OUT_F, OUT_F, 3 * OUT_F, N, E);
        // ---- layer 2, protein output -> zp[:, ci, :] ----
        k_gemm<<<g2, 256, 0, stream>>>(H1d, W2 + (size_t)(c * 4 + 1) * HID_F * OUT_F, Ya, N, HID_F, OUT_F);
        k_gemm<<<g2, 256, 0, stream>>>(H1p, W2 + (size_t)(c * 4 + 3) * HID_F * OUT_F, Yb, N, HID_F, OUT_F);
        k_agg<<<N, OUT_F, 0, stream>>>(Ya, Yb, row_ptr, col, rs_out, rs_in,
                                       ci * 4 + 1, ci * 4 + 3,
                                       b2 + (size_t)(c * 4 + 1) * OUT_F, b2 + (size_t)(c * 4 + 3) * OUT_F,
                                       zp + (size_t)ci * OUT_F, OUT_F, 3 * OUT_F, N, E);
    }

    // ---- semantic attention ----
    dim3 agrid(N, 2);
    k_attn_w<<<agrid, 128, 0, stream>>>(zd, zp, Wp, bp, q, w_all, N);
    k_beta<<<2, 256, 0, stream>>>(w_all, beta_ws, out + (size_t)2 * N * OUT_F, N);
    k_emb<<<agrid, 128, 0, stream>>>(zd, zp, beta_ws, out, N);
}

// Round 3
// 2361.550 us; speedup vs baseline: 1.6200x; 1.6200x over previous
//
#include <hip/hip_runtime.h>
#include <math.h>

// ---------------------------------------------------------------------------
// MCKRL round 3: same as round 2 (fp16 MFMA GEMM 128x128/BK64 swizzled LDS +
// global_load_lds, LDS-histogram CSR build, fp16 gather inputs) with the
// host/device chan_of compile fix.
// ---------------------------------------------------------------------------

#define IN_F  512
#define HID_F 256
#define OUT_F 128
#define NG    12       // 3 live channels x 4 relations
#define NPART 8
#define RANGE 3750     // 30000 / NPART

typedef _Float16 f16x8 __attribute__((ext_vector_type(8)));
typedef float    f32x4 __attribute__((ext_vector_type(4)));

#define AS1 __attribute__((address_space(1)))
#define AS3 __attribute__((address_space(3)))

__device__ __forceinline__ void gld16(const void* g, void* l) {
    __builtin_amdgcn_global_load_lds((const AS1 void*)g, (AS3 void*)l, 16, 0, 0);
}

__host__ __device__ __forceinline__ int chan_of(int ci) { return ci == 0 ? 0 : ci + 1; } // {0,2,3}

// ---------------- degrees via range-partitioned LDS histograms ------------
// grid (NG, NPART). Writes deg_in (int) + rs_out/rs_in (deg^-1/2) directly.
__global__ __launch_bounds__(512) void k_deg2(const int* __restrict__ src,
                                              const int* __restrict__ dst,
                                              int* __restrict__ deg_in,
                                              float* __restrict__ rs_out,
                                              float* __restrict__ rs_in,
                                              int N, int E) {
    __shared__ int ho[RANGE], hi[RANGE];
    int g = blockIdx.x, p = blockIdx.y, t = threadIdx.x;
    for (int i = t; i < RANGE; i += 512) { ho[i] = 0; hi[i] = 0; }
    __syncthreads();
    int ci = g >> 2, c = chan_of(ci), r = g & 3;
    const int* sp = src + (size_t)(c * 4 + r) * E;
    const int* dp = dst + (size_t)(c * 4 + r) * E;
    int lo = p * RANGE;
    for (int e = t; e < E; e += 512) {
        int s = sp[e] - lo;
        int d = dp[e] - lo;
        if ((unsigned)s < (unsigned)RANGE) atomicAdd(&ho[s], 1);
        if ((unsigned)d < (unsigned)RANGE) atomicAdd(&hi[d], 1);
    }
    __syncthreads();
    for (int i = t; i < RANGE; i += 512) {
        int node = lo + i;
        if (node < N) {
            deg_in[(size_t)g * N + node] = hi[i];
            rs_out[(size_t)g * N + node] = rsqrtf(fmaxf((float)ho[i], 1.0f));
            rs_in [(size_t)g * N + node] = rsqrtf(fmaxf((float)hi[i], 1.0f));
        }
    }
}

// ---------------- exclusive scan of deg_in -> row_ptr ---------------------
__global__ __launch_bounds__(1024) void k_scan(const int* __restrict__ deg_in,
                                               int* __restrict__ row_ptr, int N) {
    int g = blockIdx.x;
    const int* deg = deg_in + (size_t)g * N;
    int* rp = row_ptr + (size_t)g * (N + 1);
    __shared__ int buf[1024];
    __shared__ int s_run;
    int tid = threadIdx.x;
    if (tid == 0) s_run = 0;
    __syncthreads();
    for (int base = 0; base < N; base += 1024) {
        int i = base + tid;
        int v = (i < N) ? deg[i] : 0;
        buf[tid] = v;
        __syncthreads();
        for (int off = 1; off < 1024; off <<= 1) {
            int t = (tid >= off) ? buf[tid - off] : 0;
            __syncthreads();
            buf[tid] += t;
            __syncthreads();
        }
        int run = s_run;
        if (i < N) rp[i] = run + buf[tid] - v;
        __syncthreads();
        if (tid == 0) s_run = run + buf[1023];
        __syncthreads();
    }
    if (tid == 0) rp[N] = s_run;
}

// ---------------- CSR fill via LDS cursors (no global atomics) ------------
__global__ __launch_bounds__(512) void k_fill2(const int* __restrict__ src,
                                               const int* __restrict__ dst,
                                               const int* __restrict__ row_ptr,
                                               int* __restrict__ col, int N, int E) {
    __shared__ int cur[RANGE];
    int g = blockIdx.x, p = blockIdx.y, t = threadIdx.x;
    int lo = p * RANGE;
    const int* rp = row_ptr + (size_t)g * (N + 1);
    for (int i = t; i < RANGE; i += 512) cur[i] = rp[lo + i];
    __syncthreads();
    int ci = g >> 2, c = chan_of(ci), r = g & 3;
    const int* sp = src + (size_t)(c * 4 + r) * E;
    const int* dp = dst + (size_t)(c * 4 + r) * E;
    int* cg = col + (size_t)g * E;
    for (int e = t; e < E; e += 512) {
        int s = sp[e];
        int d = dp[e] - lo;
        if ((unsigned)d < (unsigned)RANGE) {
            int pos = atomicAdd(&cur[d], 1);
            cg[pos] = s;
        }
    }
}

// ---------------- fp32 -> fp16 elementwise (n multiple of 8) --------------
__global__ void k_cvt16(const float* __restrict__ in, _Float16* __restrict__ out,
                        size_t n) {
    size_t i = ((size_t)blockIdx.x * 256 + threadIdx.x) * 8;
    if (i >= n) return;
    float4 a = *(const float4*)(in + i);
    float4 b = *(const float4*)(in + i + 4);
    f16x8 v;
    v[0] = (_Float16)a.x; v[1] = (_Float16)a.y; v[2] = (_Float16)a.z; v[3] = (_Float16)a.w;
    v[4] = (_Float16)b.x; v[5] = (_Float16)b.y; v[6] = (_Float16)b.z; v[7] = (_Float16)b.w;
    *(f16x8*)(out + i) = v;
}

// ------- weight transpose+convert: W[gphys][K][Nn] f32 -> Wt[glive][Nn][K] f16
__global__ __launch_bounds__(256) void k_cvtT(const float* __restrict__ W,
                                              _Float16* __restrict__ Wt,
                                              int K, int Nn) {
    __shared__ float tile[32][33];
    int gi = blockIdx.z, ci = gi >> 2, c = chan_of(ci), r = gi & 3;
    const float* Wg = W + (size_t)(c * 4 + r) * K * Nn;
    _Float16* Wo = Wt + (size_t)gi * K * Nn;
    int k0 = blockIdx.x * 32, n0 = blockIdx.y * 32;
    int tx = threadIdx.x & 31, ty = threadIdx.x >> 5;   // 32 x 8
    for (int yy = ty; yy < 32; yy += 8)
        tile[yy][tx] = Wg[(size_t)(k0 + yy) * Nn + n0 + tx];
    __syncthreads();
    for (int yy = ty; yy < 32; yy += 8)
        Wo[(size_t)(n0 + yy) * K + k0 + tx] = (_Float16)tile[tx][yy];
}

// ---------------- fp16 MFMA GEMM: C[M,Nn] = A[M,K] @ Bt[Nn,K]^T -----------
// 128x128 tile, BK=64, 256 threads (4 waves 2x2), 16x16x32_f16 MFMA.
// LDS tiles [128 rows][8 slots of 16B], slot XOR-swizzled by (row&7);
// global source pre-swizzled so global_load_lds dest stays linear.
__global__ __launch_bounds__(256) void k_gemm16(const _Float16* __restrict__ A,
                                                const _Float16* __restrict__ Bt,
                                                _Float16* __restrict__ C,
                                                int M, int K, int Nn) {
    __shared__ __align__(16) _Float16 As[128 * 64];
    __shared__ __align__(16) _Float16 Bs[128 * 64];
    int t = threadIdx.x;
    int lane = t & 63, wid = t >> 6;
    int wm = wid >> 1, wn = wid & 1;
    int brow = blockIdx.y * 128, bcol = blockIdx.x * 128;

    f32x4 acc[4][4] = {};

    int mrow = lane & 15;
    int khalf = lane >> 4;   // 0..3

    for (int k0 = 0; k0 < K; k0 += 64) {
        __syncthreads();   // all waves done reading previous tiles
#pragma unroll
        for (int i = 0; i < 4; ++i) {
            int L = t + i * 256;
            int row = L >> 3, spp = L & 7;
            int sg = spp ^ (row & 7);           // pre-swizzled global slot
            int ra = brow + row; if (ra > M - 1) ra = M - 1;
            gld16((const void*)(A + (size_t)ra * K + (size_t)(k0 + sg * 8)),
                  (void*)(As + (size_t)(i * 256 + wid * 64) * 8));
            int rb = bcol + row;
            gld16((const void*)(Bt + (size_t)rb * K + (size_t)(k0 + sg * 8)),
                  (void*)(Bs + (size_t)(i * 256 + wid * 64) * 8));
        }
        __syncthreads();   // implies vmcnt(0) drain
#pragma unroll
        for (int ks = 0; ks < 2; ++ks) {
            f16x8 af[4], bf[4];
#pragma unroll
            for (int mi = 0; mi < 4; ++mi) {
                int r = wm * 64 + mi * 16 + mrow;
                int s = ks * 4 + khalf;
                int ph = s ^ (r & 7);
                af[mi] = *(const f16x8*)(As + r * 64 + ph * 8);
            }
#pragma unroll
            for (int ni = 0; ni < 4; ++ni) {
                int r = wn * 64 + ni * 16 + mrow;
                int s = ks * 4 + khalf;
                int ph = s ^ (r & 7);
                bf[ni] = *(const f16x8*)(Bs + r * 64 + ph * 8);
            }
#pragma unroll
            for (int mi = 0; mi < 4; ++mi)
#pragma unroll
                for (int ni = 0; ni < 4; ++ni)
                    acc[mi][ni] = __builtin_amdgcn_mfma_f32_16x16x32_f16(
                        af[mi], bf[ni], acc[mi][ni], 0, 0, 0);
        }
    }
#pragma unroll
    for (int mi = 0; mi < 4; ++mi) {
#pragma unroll
        for (int r = 0; r < 4; ++r) {
            int row = brow + wm * 64 + mi * 16 + (lane >> 4) * 4 + r;
            if (row < M) {
#pragma unroll
                for (int ni = 0; ni < 4; ++ni) {
                    int colx = bcol + wn * 64 + ni * 16 + (lane & 15);
                    C[(size_t)row * Nn + colx] = (_Float16)acc[mi][ni][r];
                }
            }
        }
    }
}

// ------- fused two-relation gather + norm + bias + relu (fp16 Y in) -------
__global__ void k_agg(const _Float16* __restrict__ Ya, const _Float16* __restrict__ Yb,
                      const int* __restrict__ row_ptr, const int* __restrict__ col,
                      const float* __restrict__ rs_out, const float* __restrict__ rs_in,
                      int ga, int gb,
                      const float* __restrict__ ba, const float* __restrict__ bb,
                      _Float16* __restrict__ out16, float* __restrict__ out32,
                      int F, int ostride, int N, int E) {
    int i = blockIdx.x;
    int f = threadIdx.x;  // blockDim.x == F
    float acc = ba[f] + bb[f];
    {
        const int* rp = row_ptr + (size_t)ga * (N + 1);
        const int* cg = col + (size_t)ga * E;
        const float* ro = rs_out + (size_t)ga * N;
        int beg = rp[i], end = rp[i + 1];
        float s = 0.0f;
        int sn = (beg < end) ? cg[beg] : 0;
        for (int e = beg; e < end; ++e) {
            int sn1 = (e + 1 < end) ? cg[e + 1] : 0;
            s += ro[sn] * (float)Ya[(size_t)sn * F + f];
            sn = sn1;
        }
        acc += rs_in[(size_t)ga * N + i] * s;
    }
    {
        const int* rp = row_ptr + (size_t)gb * (N + 1);
        const int* cg = col + (size_t)gb * E;
        const float* ro = rs_out + (size_t)gb * N;
        int beg = rp[i], end = rp[i + 1];
        float s = 0.0f;
        int sn = (beg < end) ? cg[beg] : 0;
        for (int e = beg; e < end; ++e) {
            int sn1 = (e + 1 < end) ? cg[e + 1] : 0;
            s += ro[sn] * (float)Yb[(size_t)sn * F + f];
            sn = sn1;
        }
        acc += rs_in[(size_t)gb * N + i] * s;
    }
    float v = fmaxf(acc, 0.0f);
    if (out16) out16[(size_t)i * F + f] = (_Float16)v;
    else       out32[(size_t)i * ostride + f] = v;
}

// ---------------- semantic attention: per-node w scores -------------------
__global__ __launch_bounds__(128) void k_attn_w(const float* __restrict__ zd,
                                                const float* __restrict__ zp,
                                                const float* __restrict__ Wp,
                                                const float* __restrict__ bp,
                                                const float* __restrict__ q,
                                                float* __restrict__ w_all, int N) {
    int i = blockIdx.x, side = blockIdx.y;
    const float* z = side ? zp : zd;
    int f = threadIdx.x;  // 128
    __shared__ float zl[3][128];
#pragma unroll
    for (int k = 0; k < 3; ++k) zl[k][f] = z[(size_t)i * 384 + k * 128 + f];
    __syncthreads();
    float a0 = bp[f], a1 = bp[f], a2 = bp[f];
    for (int j = 0; j < 128; ++j) {
        float wv = Wp[j * 128 + f];
        a0 = fmaf(zl[0][j], wv, a0);
        a1 = fmaf(zl[1][j], wv, a1);
        a2 = fmaf(zl[2][j], wv, a2);
    }
    float qf = q[f];
    float tv[3] = {tanhf(a0) * qf, tanhf(a1) * qf, tanhf(a2) * qf};
    __shared__ float red[128];
#pragma unroll
    for (int k = 0; k < 3; ++k) {
        __syncthreads();
        red[f] = tv[k];
        __syncthreads();
        for (int off = 64; off > 0; off >>= 1) {
            if (f < off) red[f] += red[f + off];
            __syncthreads();
        }
        if (f == 0) w_all[((size_t)side * 3 + k) * N + i] = red[0];
    }
}

// ---------------- beta: deterministic reduce + softmax --------------------
__global__ __launch_bounds__(256) void k_beta(const float* __restrict__ w_all,
                                              float* __restrict__ beta_ws,
                                              float* __restrict__ beta_out, int N) {
    int side = blockIdx.x;
    int tid = threadIdx.x;
    __shared__ float red[256];
    float sums[3];
    for (int k = 0; k < 3; ++k) {
        float s = 0.0f;
        for (int i = tid; i < N; i += 256) s += w_all[((size_t)side * 3 + k) * N + i];
        red[tid] = s;
        __syncthreads();
        for (int off = 128; off > 0; off >>= 1) {
            if (tid < off) red[tid] += red[tid + off];
            __syncthreads();
        }
        sums[k] = red[0];
        __syncthreads();
    }
    if (tid == 0) {
        float inv = 1.0f / (float)N;
        float m0 = sums[0] * inv, m1 = sums[1] * inv, m2 = sums[2] * inv;
        float mx = fmaxf(m0, fmaxf(m1, m2));
        float e0 = expf(m0 - mx), e1 = expf(m1 - mx), e2 = expf(m2 - mx);
        float denom = e0 + e1 + e2;
        float b0 = e0 / denom, b1 = e1 / denom, b2 = e2 / denom;
        beta_ws[side * 3 + 0] = b0; beta_out[side * 3 + 0] = b0;
        beta_ws[side * 3 + 1] = b1; beta_out[side * 3 + 1] = b1;
        beta_ws[side * 3 + 2] = b2; beta_out[side * 3 + 2] = b2;
    }
}

// ---------------- emb = sum_k beta[k] * z[:,k,:] --------------------------
__global__ __launch_bounds__(128) void k_emb(const float* __restrict__ zd,
                                             const float* __restrict__ zp,
                                             const float* __restrict__ beta_ws,
                                             float* __restrict__ out, int N) {
    int i = blockIdx.x, side = blockIdx.y, f = threadIdx.x;
    const float* z = side ? zp : zd;
    const float* b = beta_ws + side * 3;
    float v = b[0] * z[(size_t)i * 384 + f]
            + b[1] * z[(size_t)i * 384 + 128 + f]
            + b[2] * z[(size_t)i * 384 + 256 + f];
    out[(size_t)side * N * 128 + (size_t)i * 128 + f] = v;
}

// ---------------------------------------------------------------------------
extern "C" void kernel_launch(void* const* d_in, const int* in_sizes, int n_in,
                              void* d_out, int out_size, void* d_ws, size_t ws_size,
                              hipStream_t stream) {
    const float* x_drug = (const float*)d_in[0];
    const float* x_pro  = (const float*)d_in[1];
    const int*   src    = (const int*)d_in[2];
    const int*   dst    = (const int*)d_in[3];
    const float* W1     = (const float*)d_in[4];
    const float* b1     = (const float*)d_in[5];
    const float* W2     = (const float*)d_in[6];
    const float* b2     = (const float*)d_in[7];
    const float* Wp     = (const float*)d_in[8];
    const float* bp     = (const float*)d_in[9];
    const float* q      = (const float*)d_in[10];
    float* out = (float*)d_out;

    const int N = in_sizes[0] / IN_F;      // 30000
    const int E = in_sizes[2] / 16;        // 250000

    size_t off = 0;
    auto alloc = [&](size_t bytes) -> void* {
        void* p = (char*)d_ws + off;
        off += (bytes + 255) & ~(size_t)255;
        return p;
    };
    int*      deg_in  = (int*)alloc((size_t)NG * N * 4);
    int*      row_ptr = (int*)alloc((size_t)NG * (N + 1) * 4);
    int*      col     = (int*)alloc((size_t)NG * E * 4);
    float*    rs_out  = (float*)alloc((size_t)NG * N * 4);
    float*    rs_in   = (float*)alloc((size_t)NG * N * 4);
    _Float16* xh_d    = (_Float16*)alloc((size_t)N * IN_F * 2);
    _Float16* xh_p    = (_Float16*)alloc((size_t)N * IN_F * 2);
    _Float16* W1t     = (_Float16*)alloc((size_t)NG * IN_F * HID_F * 2);
    _Float16* W2t     = (_Float16*)alloc((size_t)NG * HID_F * OUT_F * 2);
    _Float16* Ya      = (_Float16*)alloc((size_t)N * HID_F * 2);
    _Float16* Yb      = (_Float16*)alloc((size_t)N * HID_F * 2);
    _Float16* H1d     = (_Float16*)alloc((size_t)N * HID_F * 2);
    _Float16* H1p     = (_Float16*)alloc((size_t)N * HID_F * 2);
    float*    zd      = (float*)alloc((size_t)N * 3 * OUT_F * 4);
    float*    zp      = (float*)alloc((size_t)N * 3 * OUT_F * 4);
    float*    w_all   = (float*)alloc((size_t)2 * 3 * N * 4);
    float*    beta_ws = (float*)alloc(64);
    (void)ws_size; (void)n_in; (void)out_size;

    // ---- CSR build (LDS histograms; no global atomics) ----
    dim3 pg(NG, NPART);
    k_deg2<<<pg, 512, 0, stream>>>(src, dst, deg_in, rs_out, rs_in, N, E);
    k_scan<<<NG, 1024, 0, stream>>>(deg_in, row_ptr, N);
    k_fill2<<<pg, 512, 0, stream>>>(src, dst, row_ptr, col, N, E);

    // ---- fp16 conversions ----
    size_t nx = (size_t)N * IN_F;
    k_cvt16<<<(int)((nx / 8 + 255) / 256), 256, 0, stream>>>(x_drug, xh_d, nx);
    k_cvt16<<<(int)((nx / 8 + 255) / 256), 256, 0, stream>>>(x_pro,  xh_p, nx);
    k_cvtT<<<dim3(IN_F / 32, HID_F / 32, NG), 256, 0, stream>>>(W1, W1t, IN_F, HID_F);
    k_cvtT<<<dim3(HID_F / 32, OUT_F / 32, NG), 256, 0, stream>>>(W2, W2t, HID_F, OUT_F);

    dim3 g1(HID_F / 128, (N + 127) / 128);   // layer-1 GEMM grid
    dim3 g2(OUT_F / 128, (N + 127) / 128);   // layer-2 GEMM grid

    for (int ci = 0; ci < 3; ++ci) {
        int c = chan_of(ci);
        // layer 1, drug out: rel 0 (xd->d) + rel 2 (xp->d)
        k_gemm16<<<g1, 256, 0, stream>>>(xh_d, W1t + (size_t)(ci * 4 + 0) * IN_F * HID_F, Ya, N, IN_F, HID_F);
        k_gemm16<<<g1, 256, 0, stream>>>(xh_p, W1t + (size_t)(ci * 4 + 2) * IN_F * HID_F, Yb, N, IN_F, HID_F);
        k_agg<<<N, HID_F, 0, stream>>>(Ya, Yb, row_ptr, col, rs_out, rs_in,
                                       ci * 4 + 0, ci * 4 + 2,
                                       b1 + (size_t)(c * 4 + 0) * HID_F, b1 + (size_t)(c * 4 + 2) * HID_F,
                                       H1d, nullptr, HID_F, HID_F, N, E);
        // layer 1, protein out: rel 1 (xd->p) + rel 3 (xp->p)
        k_gemm16<<<g1, 256, 0, stream>>>(xh_d, W1t + (size_t)(ci * 4 + 1) * IN_F * HID_F, Ya, N, IN_F, HID_F);
        k_gemm16<<<g1, 256, 0, stream>>>(xh_p, W1t + (size_t)(ci * 4 + 3) * IN_F * HID_F, Yb, N, IN_F, HID_F);
        k_agg<<<N, HID_F, 0, stream>>>(Ya, Yb, row_ptr, col, rs_out, rs_in,
                                       ci * 4 + 1, ci * 4 + 3,
                                       b1 + (size_t)(c * 4 + 1) * HID_F, b1 + (size_t)(c * 4 + 3) * HID_F,
                                       H1p, nullptr, HID_F, HID_F, N, E);
        // layer 2, drug out -> zd[:, ci, :]
        k_gemm16<<<g2, 256, 0, stream>>>(H1d, W2t + (size_t)(ci * 4 + 0) * HID_F * OUT_F, Ya, N, HID_F, OUT_F);
        k_gemm16<<<g2, 256, 0, stream>>>(H1p, W2t + (size_t)(ci * 4 + 2) * HID_F * OUT_F, Yb, N, HID_F, OUT_F);
        k_agg<<<N, OUT_F, 0, stream>>>(Ya, Yb, row_ptr, col, rs_out, rs_in,
                                       ci * 4 + 0, ci * 4 + 2,
                                       b2 + (size_t)(c * 4 + 0) * OUT_F, b2 + (size_t)(c * 4 + 2) * OUT_F,
                                       nullptr, zd + (size_t)ci * OUT_F, OUT_F, 3 * OUT_F, N, E);
        // layer 2, protein out -> zp[:, ci, :]
        k_gemm16<<<g2, 256, 0, stream>>>(H1d, W2t + (size_t)(ci * 4 + 1) * HID_F * OUT_F, Ya, N, HID_F, OUT_F);
        k_gemm16<<<g2, 256, 0, stream>>>(H1p, W2t + (size_t)(ci * 4 + 3) * HID_F * OUT_F, Yb, N, HID_F, OUT_F);
        k_agg<<<N, OUT_F, 0, stream>>>(Ya, Yb, row_ptr, col, rs_out, rs_in,
                                       ci * 4 + 1, ci * 4 + 3,
                                       b2 + (size_t)(c * 4 + 1) * OUT_F, b2 + (size_t)(c * 4 + 3) * OUT_F,
                                       nullptr, zp + (size_t)ci * OUT_F, OUT_F, 3 * OUT_F, N, E);
    }

    // ---- semantic attention ----
    dim3 agrid(N, 2);
    k_attn_w<<<agrid, 128, 0, stream>>>(zd, zp, Wp, bp, q, w_all, N);
    k_beta<<<2, 256, 0, stream>>>(w_all, beta_ws, out + (size_t)2 * N * OUT_F, N);
    k_emb<<<agrid, 128, 0, stream>>>(zd, zp, beta_ws, out, N);
}

// Round 4
// 2280.998 us; speedup vs baseline: 1.6772x; 1.0353x over previous
//
#include <hip/hip_runtime.h>
#include <math.h>

// ---------------------------------------------------------------------------
// MCKRL round 4: NPART 8->32 for CSR build (latency-bound fix), z-batched
// GEMMs (24 launches -> 6), batched agg (12 -> 6), LDS-cached attn_w,
// fp16 z buffers, shuffle scan. Channel 1 of 4 remains dead code.
// ---------------------------------------------------------------------------

#define IN_F  512
#define HID_F 256
#define OUT_F 128
#define NG    12       // 3 live channels x 4 relations
#define NPART 32
#define RANGE 940      // 32*940 = 30080 >= 30000

typedef _Float16 f16x8 __attribute__((ext_vector_type(8)));
typedef float    f32x4 __attribute__((ext_vector_type(4)));

#define AS1 __attribute__((address_space(1)))
#define AS3 __attribute__((address_space(3)))

__device__ __forceinline__ void gld16(const void* g, void* l) {
    __builtin_amdgcn_global_load_lds((const AS1 void*)g, (AS3 void*)l, 16, 0, 0);
}

__host__ __device__ __forceinline__ int chan_of(int ci) { return ci == 0 ? 0 : ci + 1; } // {0,2,3}

// ---------------- degrees via range-partitioned LDS histograms ------------
__global__ __launch_bounds__(512) void k_deg2(const int* __restrict__ src,
                                              const int* __restrict__ dst,
                                              int* __restrict__ deg_in,
                                              float* __restrict__ rs_out,
                                              float* __restrict__ rs_in,
                                              int N, int E) {
    __shared__ int ho[RANGE], hi[RANGE];
    int g = blockIdx.x, p = blockIdx.y, t = threadIdx.x;
    for (int i = t; i < RANGE; i += 512) { ho[i] = 0; hi[i] = 0; }
    __syncthreads();
    int ci = g >> 2, c = chan_of(ci), r = g & 3;
    const int* sp = src + (size_t)(c * 4 + r) * E;
    const int* dp = dst + (size_t)(c * 4 + r) * E;
    int lo = p * RANGE;
    for (int e = t; e < E; e += 512) {
        int s = sp[e] - lo;
        int d = dp[e] - lo;
        if ((unsigned)s < (unsigned)RANGE) atomicAdd(&ho[s], 1);
        if ((unsigned)d < (unsigned)RANGE) atomicAdd(&hi[d], 1);
    }
    __syncthreads();
    for (int i = t; i < RANGE; i += 512) {
        int node = lo + i;
        if (node < N) {
            deg_in[(size_t)g * N + node] = hi[i];
            rs_out[(size_t)g * N + node] = rsqrtf(fmaxf((float)ho[i], 1.0f));
            rs_in [(size_t)g * N + node] = rsqrtf(fmaxf((float)hi[i], 1.0f));
        }
    }
}

// ---------------- exclusive scan of deg_in -> row_ptr (shuffle) -----------
__global__ __launch_bounds__(1024) void k_scan(const int* __restrict__ deg_in,
                                               int* __restrict__ row_ptr, int N) {
    int g = blockIdx.x;
    const int* dg = deg_in + (size_t)g * N;
    int* rp = row_ptr + (size_t)g * (N + 1);
    __shared__ int wsum[16];
    int tid = threadIdx.x;
    int lane = tid & 63, wv = tid >> 6;
    int run = 0;
    for (int basei = 0; basei < N; basei += 1024) {
        int i = basei + tid;
        int v = (i < N) ? dg[i] : 0;
        int x = v;
#pragma unroll
        for (int off = 1; off < 64; off <<= 1) {
            int y = __shfl_up(x, off);
            if (lane >= off) x += y;
        }
        if (lane == 63) wsum[wv] = x;
        __syncthreads();
        if (wv == 0) {
            int s = (lane < 16) ? wsum[lane] : 0;
#pragma unroll
            for (int off = 1; off < 16; off <<= 1) {
                int y = __shfl_up(s, off);
                if (lane >= off) s += y;
            }
            if (lane < 16) wsum[lane] = s;
        }
        __syncthreads();
        int woff = wv ? wsum[wv - 1] : 0;
        if (i < N) rp[i] = run + woff + x - v;
        run += wsum[15];
        __syncthreads();  // wsum reused next chunk
    }
    if (tid == 0) rp[N] = run;
}

// ---------------- CSR fill via LDS cursors --------------------------------
__global__ __launch_bounds__(512) void k_fill2(const int* __restrict__ src,
                                               const int* __restrict__ dst,
                                               const int* __restrict__ row_ptr,
                                               int* __restrict__ col, int N, int E) {
    __shared__ int cur[RANGE];
    int g = blockIdx.x, p = blockIdx.y, t = threadIdx.x;
    int lo = p * RANGE;
    const int* rp = row_ptr + (size_t)g * (N + 1);
    for (int i = t; i < RANGE; i += 512) cur[i] = (lo + i < N) ? rp[lo + i] : 0;
    __syncthreads();
    int ci = g >> 2, c = chan_of(ci), r = g & 3;
    const int* sp = src + (size_t)(c * 4 + r) * E;
    const int* dp = dst + (size_t)(c * 4 + r) * E;
    int* cg = col + (size_t)g * E;
    for (int e = t; e < E; e += 512) {
        int s = sp[e];
        int d = dp[e] - lo;
        if ((unsigned)d < (unsigned)RANGE) {
            int pos = atomicAdd(&cur[d], 1);
            cg[pos] = s;
        }
    }
}

// ---------------- fp32 -> fp16 elementwise (n multiple of 8) --------------
__global__ void k_cvt16(const float* __restrict__ in, _Float16* __restrict__ out,
                        size_t n) {
    size_t i = ((size_t)blockIdx.x * 256 + threadIdx.x) * 8;
    if (i >= n) return;
    float4 a = *(const float4*)(in + i);
    float4 b = *(const float4*)(in + i + 4);
    f16x8 v;
    v[0] = (_Float16)a.x; v[1] = (_Float16)a.y; v[2] = (_Float16)a.z; v[3] = (_Float16)a.w;
    v[4] = (_Float16)b.x; v[5] = (_Float16)b.y; v[6] = (_Float16)b.z; v[7] = (_Float16)b.w;
    *(f16x8*)(out + i) = v;
}

// ------- weight transpose+convert into concatenated f16 layout ------------
// W phys [4][4][K][Nn] f32 -> out[(ci*2 + (r>>1)) * 2*Nn + (r&1)*Nn + n][k] f16
__global__ __launch_bounds__(256) void k_cvtT(const float* __restrict__ W,
                                              _Float16* __restrict__ out,
                                              int K, int Nn) {
    __shared__ float tile[32][33];
    int gi = blockIdx.z, ci = gi >> 2, c = chan_of(ci), r = gi & 3;
    const float* Wg = W + (size_t)(c * 4 + r) * K * Nn;
    _Float16* Wo = out + ((size_t)(ci * 2 + (r >> 1)) * 2 * Nn + (size_t)(r & 1) * Nn) * K;
    int k0 = blockIdx.x * 32, n0 = blockIdx.y * 32;
    int tx = threadIdx.x & 31, ty = threadIdx.x >> 5;   // 32 x 8
    for (int yy = ty; yy < 32; yy += 8)
        tile[yy][tx] = Wg[(size_t)(k0 + yy) * Nn + n0 + tx];
    __syncthreads();
    for (int yy = ty; yy < 32; yy += 8)
        Wo[(size_t)(n0 + yy) * K + k0 + tx] = (_Float16)tile[tx][yy];
}

// ---------------- z-batched fp16 MFMA GEMM: C = A @ Bt^T ------------------
// 128x128 tile, BK=64, 256 threads (4 waves 2x2), 16x16x32_f16 MFMA.
__global__ __launch_bounds__(256) void k_gemm16(const _Float16* __restrict__ A0, size_t Azs,
                                                const _Float16* __restrict__ B0, size_t Bzs,
                                                _Float16* __restrict__ C0, size_t Czs,
                                                int M, int K, int Nn) {
    const _Float16* A = A0 + (size_t)blockIdx.z * Azs;
    const _Float16* Bt = B0 + (size_t)blockIdx.z * Bzs;
    _Float16* C = C0 + (size_t)blockIdx.z * Czs;
    __shared__ __align__(16) _Float16 As[128 * 64];
    __shared__ __align__(16) _Float16 Bs[128 * 64];
    int t = threadIdx.x;
    int lane = t & 63, wid = t >> 6;
    int wm = wid >> 1, wn = wid & 1;
    int brow = blockIdx.y * 128, bcol = blockIdx.x * 128;

    f32x4 acc[4][4] = {};
    int mrow = lane & 15;
    int khalf = lane >> 4;   // 0..3

    for (int k0 = 0; k0 < K; k0 += 64) {
        __syncthreads();
#pragma unroll
        for (int i = 0; i < 4; ++i) {
            int L = t + i * 256;
            int row = L >> 3, spp = L & 7;
            int sg = spp ^ (row & 7);           // pre-swizzled global slot
            int ra = brow + row; if (ra > M - 1) ra = M - 1;
            gld16((const void*)(A + (size_t)ra * K + (size_t)(k0 + sg * 8)),
                  (void*)(As + (size_t)(i * 256 + wid * 64) * 8));
            int rb = bcol + row;
            gld16((const void*)(Bt + (size_t)rb * K + (size_t)(k0 + sg * 8)),
                  (void*)(Bs + (size_t)(i * 256 + wid * 64) * 8));
        }
        __syncthreads();
#pragma unroll
        for (int ks = 0; ks < 2; ++ks) {
            f16x8 af[4], bf[4];
#pragma unroll
            for (int mi = 0; mi < 4; ++mi) {
                int r = wm * 64 + mi * 16 + mrow;
                int s = ks * 4 + khalf;
                int ph = s ^ (r & 7);
                af[mi] = *(const f16x8*)(As + r * 64 + ph * 8);
            }
#pragma unroll
            for (int ni = 0; ni < 4; ++ni) {
                int r = wn * 64 + ni * 16 + mrow;
                int s = ks * 4 + khalf;
                int ph = s ^ (r & 7);
                bf[ni] = *(const f16x8*)(Bs + r * 64 + ph * 8);
            }
#pragma unroll
            for (int mi = 0; mi < 4; ++mi)
#pragma unroll
                for (int ni = 0; ni < 4; ++ni)
                    acc[mi][ni] = __builtin_amdgcn_mfma_f32_16x16x32_f16(
                        af[mi], bf[ni], acc[mi][ni], 0, 0, 0);
        }
    }
#pragma unroll
    for (int mi = 0; mi < 4; ++mi) {
#pragma unroll
        for (int r = 0; r < 4; ++r) {
            int row = brow + wm * 64 + mi * 16 + (lane >> 4) * 4 + r;
            if (row < M) {
#pragma unroll
                for (int ni = 0; ni < 4; ++ni) {
                    int colx = bcol + wn * 64 + ni * 16 + (lane & 15);
                    C[(size_t)row * Nn + colx] = (_Float16)acc[mi][ni][r];
                }
            }
        }
    }
}

// ------- batched fused two-relation gather + norm + bias + relu -----------
// grid (N, 2): side = blockIdx.y. F = blockDim.x.
__global__ void k_agg(const _Float16* __restrict__ Ya0, const _Float16* __restrict__ Yb0,
                      int ystride,
                      const int* __restrict__ row_ptr, const int* __restrict__ col,
                      const float* __restrict__ rs_out, const float* __restrict__ rs_in,
                      int ga0, int gb0,
                      const float* __restrict__ ba0, const float* __restrict__ bb0,
                      _Float16* __restrict__ outb, size_t out_sidestride, int ostride,
                      int N, int E) {
    int i = blockIdx.x, side = blockIdx.y;
    int f = threadIdx.x, F = blockDim.x;
    const _Float16* Ya = Ya0 + side * F;
    const _Float16* Yb = Yb0 + side * F;
    int ga = ga0 + side, gb = gb0 + side;
    float acc = ba0[side * F + f] + bb0[side * F + f];
    {
        const int* rp = row_ptr + (size_t)ga * (N + 1);
        const int* cg = col + (size_t)ga * E;
        const float* ro = rs_out + (size_t)ga * N;
        int beg = rp[i], end = rp[i + 1];
        float s = 0.0f;
        int sn = (beg < end) ? cg[beg] : 0;
        for (int e = beg; e < end; ++e) {
            int sn1 = (e + 1 < end) ? cg[e + 1] : 0;
            s += ro[sn] * (float)Ya[(size_t)sn * ystride + f];
            sn = sn1;
        }
        acc += rs_in[(size_t)ga * N + i] * s;
    }
    {
        const int* rp = row_ptr + (size_t)gb * (N + 1);
        const int* cg = col + (size_t)gb * E;
        const float* ro = rs_out + (size_t)gb * N;
        int beg = rp[i], end = rp[i + 1];
        float s = 0.0f;
        int sn = (beg < end) ? cg[beg] : 0;
        for (int e = beg; e < end; ++e) {
            int sn1 = (e + 1 < end) ? cg[e + 1] : 0;
            s += ro[sn] * (float)Yb[(size_t)sn * ystride + f];
            sn = sn1;
        }
        acc += rs_in[(size_t)gb * N + i] * s;
    }
    outb[side * out_sidestride + (size_t)i * ostride + f] = (_Float16)fmaxf(acc, 0.0f);
}

// ---------------- semantic attention: per-node w scores -------------------
// grid ((N/8), 2), 256 threads. Wp cached in LDS as fp16; 8 nodes per block.
__global__ __launch_bounds__(256) void k_attn_w(const _Float16* __restrict__ z,
                                                const float* __restrict__ Wp,
                                                const float* __restrict__ bp,
                                                const float* __restrict__ q,
                                                float* __restrict__ w_all, int N) {
    __shared__ _Float16 WpL[128 * 128];
    __shared__ float zl[8][3][128];
    __shared__ float part[4][3];
    int tid = threadIdx.x;
    int side = blockIdx.y;
    int base = blockIdx.x * 8;
    const _Float16* zb = z + (size_t)side * N * 384 + (size_t)base * 384;
    for (int idx = tid; idx < 128 * 128; idx += 256) WpL[idx] = (_Float16)Wp[idx];
    for (int idx = tid; idx < 8 * 384; idx += 256) ((float*)zl)[idx] = (float)zb[idx];
    __syncthreads();
    int f = tid & 127, half = tid >> 7;
    int lane = tid & 63, wv = tid >> 6;     // waves 0,1 = half0; 2,3 = half1
    float bpf = bp[f], qf = q[f];
    for (int it = 0; it < 4; ++it) {
        int n = it * 2 + half;              // local node for this half
        float a0 = bpf, a1 = bpf, a2 = bpf;
        for (int j = 0; j < 128; ++j) {
            float w = (float)WpL[j * 128 + f];
            a0 = fmaf(zl[n][0][j], w, a0);
            a1 = fmaf(zl[n][1][j], w, a1);
            a2 = fmaf(zl[n][2][j], w, a2);
        }
        float v[3] = { tanhf(a0) * qf, tanhf(a1) * qf, tanhf(a2) * qf };
#pragma unroll
        for (int k = 0; k < 3; ++k) {
            float x = v[k];
#pragma unroll
            for (int m = 1; m < 64; m <<= 1) x += __shfl_xor(x, m);
            if (lane == 0) part[wv][k] = x;
        }
        __syncthreads();
        if (tid < 6) {
            int h = tid / 3, k = tid % 3;
            float s = part[h * 2][k] + part[h * 2 + 1][k];
            w_all[((size_t)side * 3 + k) * N + base + it * 2 + h] = s;
        }
        __syncthreads();
    }
}

// ---------------- beta: deterministic reduce + softmax --------------------
__global__ __launch_bounds__(256) void k_beta(const float* __restrict__ w_all,
                                              float* __restrict__ beta_ws,
                                              float* __restrict__ beta_out, int N) {
    int side = blockIdx.x;
    int tid = threadIdx.x;
    __shared__ float red[256];
    float sums[3];
    for (int k = 0; k < 3; ++k) {
        float s = 0.0f;
        for (int i = tid; i < N; i += 256) s += w_all[((size_t)side * 3 + k) * N + i];
        red[tid] = s;
        __syncthreads();
        for (int off = 128; off > 0; off >>= 1) {
            if (tid < off) red[tid] += red[tid + off];
            __syncthreads();
        }
        sums[k] = red[0];
        __syncthreads();
    }
    if (tid == 0) {
        float inv = 1.0f / (float)N;
        float m0 = sums[0] * inv, m1 = sums[1] * inv, m2 = sums[2] * inv;
        float mx = fmaxf(m0, fmaxf(m1, m2));
        float e0 = expf(m0 - mx), e1 = expf(m1 - mx), e2 = expf(m2 - mx);
        float denom = e0 + e1 + e2;
        float b0 = e0 / denom, b1 = e1 / denom, b2 = e2 / denom;
        beta_ws[side * 3 + 0] = b0; beta_out[side * 3 + 0] = b0;
        beta_ws[side * 3 + 1] = b1; beta_out[side * 3 + 1] = b1;
        beta_ws[side * 3 + 2] = b2; beta_out[side * 3 + 2] = b2;
    }
}

// ---------------- emb = sum_k beta[k] * z[:,k,:] (z fp16 -> out fp32) -----
__global__ __launch_bounds__(128) void k_emb(const _Float16* __restrict__ z,
                                             const float* __restrict__ beta_ws,
                                             float* __restrict__ out, int N) {
    int i = blockIdx.x, side = blockIdx.y, f = threadIdx.x;
    const _Float16* zr = z + (size_t)side * N * 384 + (size_t)i * 384;
    const float* b = beta_ws + side * 3;
    float v = b[0] * (float)zr[f] + b[1] * (float)zr[128 + f] + b[2] * (float)zr[256 + f];
    out[(size_t)side * N * 128 + (size_t)i * 128 + f] = v;
}

// ---------------------------------------------------------------------------
extern "C" void kernel_launch(void* const* d_in, const int* in_sizes, int n_in,
                              void* d_out, int out_size, void* d_ws, size_t ws_size,
                              hipStream_t stream) {
    const float* x_drug = (const float*)d_in[0];
    const float* x_pro  = (const float*)d_in[1];
    const int*   src    = (const int*)d_in[2];
    const int*   dst    = (const int*)d_in[3];
    const float* W1     = (const float*)d_in[4];
    const float* b1     = (const float*)d_in[5];
    const float* W2     = (const float*)d_in[6];
    const float* b2     = (const float*)d_in[7];
    const float* Wp     = (const float*)d_in[8];
    const float* bp     = (const float*)d_in[9];
    const float* q      = (const float*)d_in[10];
    float* out = (float*)d_out;

    const int N = in_sizes[0] / IN_F;      // 30000
    const int E = in_sizes[2] / 16;        // 250000

    size_t off = 0;
    auto alloc = [&](size_t bytes) -> void* {
        void* p = (char*)d_ws + off;
        off += (bytes + 255) & ~(size_t)255;
        return p;
    };
    int*      deg_in  = (int*)alloc((size_t)NG * N * 4);
    int*      row_ptr = (int*)alloc((size_t)NG * (N + 1) * 4);
    int*      col     = (int*)alloc((size_t)NG * E * 4);
    float*    rs_out  = (float*)alloc((size_t)NG * N * 4);
    float*    rs_in   = (float*)alloc((size_t)NG * N * 4);
    _Float16* xh      = (_Float16*)alloc((size_t)2 * N * IN_F * 2);          // [2][N][512]
    _Float16* W1cat   = (_Float16*)alloc((size_t)6 * 2 * HID_F * IN_F * 2);  // [6][512][512]
    _Float16* W2cat   = (_Float16*)alloc((size_t)6 * 2 * OUT_F * HID_F * 2); // [6][256][256]
    _Float16* Y1      = (_Float16*)alloc((size_t)2 * N * 512 * 2);           // [2][N][512]
    _Float16* Y2      = (_Float16*)alloc((size_t)2 * N * 256 * 2);           // [2][N][256]
    _Float16* H1      = (_Float16*)alloc((size_t)2 * N * HID_F * 2);         // [2][N][256]
    _Float16* zbuf    = (_Float16*)alloc((size_t)2 * N * 384 * 2);           // [2][N][384]
    float*    w_all   = (float*)alloc((size_t)2 * 3 * N * 4);
    float*    beta_ws = (float*)alloc(64);
    (void)ws_size; (void)n_in; (void)out_size;

    // ---- CSR build ----
    dim3 pg(NG, NPART);
    k_deg2<<<pg, 512, 0, stream>>>(src, dst, deg_in, rs_out, rs_in, N, E);
    k_scan<<<NG, 1024, 0, stream>>>(deg_in, row_ptr, N);
    k_fill2<<<pg, 512, 0, stream>>>(src, dst, row_ptr, col, N, E);

    // ---- fp16 conversions ----
    size_t nx = (size_t)N * IN_F;
    k_cvt16<<<(int)((nx / 8 + 255) / 256), 256, 0, stream>>>(x_drug, xh, nx);
    k_cvt16<<<(int)((nx / 8 + 255) / 256), 256, 0, stream>>>(x_pro,  xh + nx, nx);
    k_cvtT<<<dim3(IN_F / 32, HID_F / 32, NG), 256, 0, stream>>>(W1, W1cat, IN_F, HID_F);
    k_cvtT<<<dim3(HID_F / 32, OUT_F / 32, NG), 256, 0, stream>>>(W2, W2cat, HID_F, OUT_F);

    dim3 g1(512 / 128, (N + 127) / 128, 2);   // layer-1 GEMM: K=512, Nn=512, z=2
    dim3 g2(256 / 128, (N + 127) / 128, 2);   // layer-2 GEMM: K=256, Nn=256, z=2
    dim3 agrid(N, 2);

    for (int ci = 0; ci < 3; ++ci) {
        int c = chan_of(ci);
        // layer 1: z=0: xh_d @ [W1 c r0 | W1 c r1]; z=1: xh_p @ [W1 c r2 | W1 c r3]
        k_gemm16<<<g1, 256, 0, stream>>>(xh, (size_t)N * IN_F,
                                         W1cat + (size_t)ci * 2 * 512 * 512, (size_t)512 * 512,
                                         Y1, (size_t)N * 512,
                                         N, IN_F, 512);
        // L1 agg -> H1[side][N][256]
        k_agg<<<agrid, HID_F, 0, stream>>>(Y1, Y1 + (size_t)N * 512, 512,
                                           row_ptr, col, rs_out, rs_in,
                                           ci * 4 + 0, ci * 4 + 2,
                                           b1 + (size_t)c * 4 * HID_F, b1 + (size_t)(c * 4 + 2) * HID_F,
                                           H1, (size_t)N * HID_F, HID_F, N, E);
        // layer 2: z=0: H1d @ [W2 c r0 | W2 c r1]; z=1: H1p @ [W2 c r2 | W2 c r3]
        k_gemm16<<<g2, 256, 0, stream>>>(H1, (size_t)N * HID_F,
                                         W2cat + (size_t)ci * 2 * 256 * 256, (size_t)256 * 256,
                                         Y2, (size_t)N * 256,
                                         N, HID_F, 256);
        // L2 agg -> z[side][N][384] col block ci*128
        k_agg<<<agrid, OUT_F, 0, stream>>>(Y2, Y2 + (size_t)N * 256, 256,
                                           row_ptr, col, rs_out, rs_in,
                                           ci * 4 + 0, ci * 4 + 2,
                                           b2 + (size_t)c * 4 * OUT_F, b2 + (size_t)(c * 4 + 2) * OUT_F,
                                           zbuf + (size_t)ci * OUT_F, (size_t)N * 384, 384, N, E);
    }

    // ---- semantic attention ----
    k_attn_w<<<dim3(N / 8, 2), 256, 0, stream>>>(zbuf, Wp, bp, q, w_all, N);
    k_beta<<<2, 256, 0, stream>>>(w_all, beta_ws, out + (size_t)2 * N * OUT_F, N);
    k_emb<<<agrid, OUT_F, 0, stream>>>(zbuf, beta_ws, out, N);
}

// Round 5
// 2077.910 us; speedup vs baseline: 1.8411x; 1.0977x over previous
//
#include <hip/hip_runtime.h>
#include <math.h>

// ---------------------------------------------------------------------------
// MCKRL round 5: semantic-attention projection moved from VALU kernel (246us,
// top dispatch) to the MFMA GEMM (z flat [2N*3,128] @ WpT) + wave-per-row
// tanh/q reduction. T reuses Y1 workspace. Rest identical to round 4.
// ---------------------------------------------------------------------------

#define IN_F  512
#define HID_F 256
#define OUT_F 128
#define NG    12       // 3 live channels x 4 relations
#define NPART 32
#define RANGE 940      // 32*940 = 30080 >= 30000

typedef _Float16 f16x8 __attribute__((ext_vector_type(8)));
typedef float    f32x4 __attribute__((ext_vector_type(4)));

#define AS1 __attribute__((address_space(1)))
#define AS3 __attribute__((address_space(3)))

__device__ __forceinline__ void gld16(const void* g, void* l) {
    __builtin_amdgcn_global_load_lds((const AS1 void*)g, (AS3 void*)l, 16, 0, 0);
}

__host__ __device__ __forceinline__ int chan_of(int ci) { return ci == 0 ? 0 : ci + 1; } // {0,2,3}

// ---------------- degrees via range-partitioned LDS histograms ------------
__global__ __launch_bounds__(512) void k_deg2(const int* __restrict__ src,
                                              const int* __restrict__ dst,
                                              int* __restrict__ deg_in,
                                              float* __restrict__ rs_out,
                                              float* __restrict__ rs_in,
                                              int N, int E) {
    __shared__ int ho[RANGE], hi[RANGE];
    int g = blockIdx.x, p = blockIdx.y, t = threadIdx.x;
    for (int i = t; i < RANGE; i += 512) { ho[i] = 0; hi[i] = 0; }
    __syncthreads();
    int ci = g >> 2, c = chan_of(ci), r = g & 3;
    const int* sp = src + (size_t)(c * 4 + r) * E;
    const int* dp = dst + (size_t)(c * 4 + r) * E;
    int lo = p * RANGE;
    for (int e = t; e < E; e += 512) {
        int s = sp[e] - lo;
        int d = dp[e] - lo;
        if ((unsigned)s < (unsigned)RANGE) atomicAdd(&ho[s], 1);
        if ((unsigned)d < (unsigned)RANGE) atomicAdd(&hi[d], 1);
    }
    __syncthreads();
    for (int i = t; i < RANGE; i += 512) {
        int node = lo + i;
        if (node < N) {
            deg_in[(size_t)g * N + node] = hi[i];
            rs_out[(size_t)g * N + node] = rsqrtf(fmaxf((float)ho[i], 1.0f));
            rs_in [(size_t)g * N + node] = rsqrtf(fmaxf((float)hi[i], 1.0f));
        }
    }
}

// ---------------- exclusive scan of deg_in -> row_ptr (shuffle) -----------
__global__ __launch_bounds__(1024) void k_scan(const int* __restrict__ deg_in,
                                               int* __restrict__ row_ptr, int N) {
    int g = blockIdx.x;
    const int* dg = deg_in + (size_t)g * N;
    int* rp = row_ptr + (size_t)g * (N + 1);
    __shared__ int wsum[16];
    int tid = threadIdx.x;
    int lane = tid & 63, wv = tid >> 6;
    int run = 0;
    for (int basei = 0; basei < N; basei += 1024) {
        int i = basei + tid;
        int v = (i < N) ? dg[i] : 0;
        int x = v;
#pragma unroll
        for (int off = 1; off < 64; off <<= 1) {
            int y = __shfl_up(x, off);
            if (lane >= off) x += y;
        }
        if (lane == 63) wsum[wv] = x;
        __syncthreads();
        if (wv == 0) {
            int s = (lane < 16) ? wsum[lane] : 0;
#pragma unroll
            for (int off = 1; off < 16; off <<= 1) {
                int y = __shfl_up(s, off);
                if (lane >= off) s += y;
            }
            if (lane < 16) wsum[lane] = s;
        }
        __syncthreads();
        int woff = wv ? wsum[wv - 1] : 0;
        if (i < N) rp[i] = run + woff + x - v;
        run += wsum[15];
        __syncthreads();  // wsum reused next chunk
    }
    if (tid == 0) rp[N] = run;
}

// ---------------- CSR fill via LDS cursors --------------------------------
__global__ __launch_bounds__(512) void k_fill2(const int* __restrict__ src,
                                               const int* __restrict__ dst,
                                               const int* __restrict__ row_ptr,
                                               int* __restrict__ col, int N, int E) {
    __shared__ int cur[RANGE];
    int g = blockIdx.x, p = blockIdx.y, t = threadIdx.x;
    int lo = p * RANGE;
    const int* rp = row_ptr + (size_t)g * (N + 1);
    for (int i = t; i < RANGE; i += 512) cur[i] = (lo + i < N) ? rp[lo + i] : 0;
    __syncthreads();
    int ci = g >> 2, c = chan_of(ci), r = g & 3;
    const int* sp = src + (size_t)(c * 4 + r) * E;
    const int* dp = dst + (size_t)(c * 4 + r) * E;
    int* cg = col + (size_t)g * E;
    for (int e = t; e < E; e += 512) {
        int s = sp[e];
        int d = dp[e] - lo;
        if ((unsigned)d < (unsigned)RANGE) {
            int pos = atomicAdd(&cur[d], 1);
            cg[pos] = s;
        }
    }
}

// ---------------- fp32 -> fp16 elementwise (n multiple of 8) --------------
__global__ void k_cvt16(const float* __restrict__ in, _Float16* __restrict__ out,
                        size_t n) {
    size_t i = ((size_t)blockIdx.x * 256 + threadIdx.x) * 8;
    if (i >= n) return;
    float4 a = *(const float4*)(in + i);
    float4 b = *(const float4*)(in + i + 4);
    f16x8 v;
    v[0] = (_Float16)a.x; v[1] = (_Float16)a.y; v[2] = (_Float16)a.z; v[3] = (_Float16)a.w;
    v[4] = (_Float16)b.x; v[5] = (_Float16)b.y; v[6] = (_Float16)b.z; v[7] = (_Float16)b.w;
    *(f16x8*)(out + i) = v;
}

// ------- weight transpose+convert into concatenated f16 layout ------------
// W phys [4][4][K][Nn] f32 -> out[(ci*2 + (r>>1)) * 2*Nn + (r&1)*Nn + n][k] f16
__global__ __launch_bounds__(256) void k_cvtT(const float* __restrict__ W,
                                              _Float16* __restrict__ out,
                                              int K, int Nn) {
    __shared__ float tile[32][33];
    int gi = blockIdx.z, ci = gi >> 2, c = chan_of(ci), r = gi & 3;
    const float* Wg = W + (size_t)(c * 4 + r) * K * Nn;
    _Float16* Wo = out + ((size_t)(ci * 2 + (r >> 1)) * 2 * Nn + (size_t)(r & 1) * Nn) * K;
    int k0 = blockIdx.x * 32, n0 = blockIdx.y * 32;
    int tx = threadIdx.x & 31, ty = threadIdx.x >> 5;   // 32 x 8
    for (int yy = ty; yy < 32; yy += 8)
        tile[yy][tx] = Wg[(size_t)(k0 + yy) * Nn + n0 + tx];
    __syncthreads();
    for (int yy = ty; yy < 32; yy += 8)
        Wo[(size_t)(n0 + yy) * K + k0 + tx] = (_Float16)tile[tx][yy];
}

// ------- Wp [128][128] f32 -> WpT [n][k] f16 ------------------------------
__global__ __launch_bounds__(256) void k_cvtWp(const float* __restrict__ Wp,
                                               _Float16* __restrict__ WpT) {
    __shared__ float tile[32][33];
    int k0 = blockIdx.x * 32, n0 = blockIdx.y * 32;
    int tx = threadIdx.x & 31, ty = threadIdx.x >> 5;
    for (int yy = ty; yy < 32; yy += 8)
        tile[yy][tx] = Wp[(size_t)(k0 + yy) * 128 + n0 + tx];
    __syncthreads();
    for (int yy = ty; yy < 32; yy += 8)
        WpT[(size_t)(n0 + yy) * 128 + k0 + tx] = (_Float16)tile[tx][yy];
}

// ---------------- z-batched fp16 MFMA GEMM: C = A @ Bt^T ------------------
// 128x128 tile, BK=64, 256 threads (4 waves 2x2), 16x16x32_f16 MFMA.
__global__ __launch_bounds__(256) void k_gemm16(const _Float16* __restrict__ A0, size_t Azs,
                                                const _Float16* __restrict__ B0, size_t Bzs,
                                                _Float16* __restrict__ C0, size_t Czs,
                                                int M, int K, int Nn) {
    const _Float16* A = A0 + (size_t)blockIdx.z * Azs;
    const _Float16* Bt = B0 + (size_t)blockIdx.z * Bzs;
    _Float16* C = C0 + (size_t)blockIdx.z * Czs;
    __shared__ __align__(16) _Float16 As[128 * 64];
    __shared__ __align__(16) _Float16 Bs[128 * 64];
    int t = threadIdx.x;
    int lane = t & 63, wid = t >> 6;
    int wm = wid >> 1, wn = wid & 1;
    int brow = blockIdx.y * 128, bcol = blockIdx.x * 128;

    f32x4 acc[4][4] = {};
    int mrow = lane & 15;
    int khalf = lane >> 4;   // 0..3

    for (int k0 = 0; k0 < K; k0 += 64) {
        __syncthreads();
#pragma unroll
        for (int i = 0; i < 4; ++i) {
            int L = t + i * 256;
            int row = L >> 3, spp = L & 7;
            int sg = spp ^ (row & 7);           // pre-swizzled global slot
            int ra = brow + row; if (ra > M - 1) ra = M - 1;
            gld16((const void*)(A + (size_t)ra * K + (size_t)(k0 + sg * 8)),
                  (void*)(As + (size_t)(i * 256 + wid * 64) * 8));
            int rb = bcol + row;
            gld16((const void*)(Bt + (size_t)rb * K + (size_t)(k0 + sg * 8)),
                  (void*)(Bs + (size_t)(i * 256 + wid * 64) * 8));
        }
        __syncthreads();
#pragma unroll
        for (int ks = 0; ks < 2; ++ks) {
            f16x8 af[4], bf[4];
#pragma unroll
            for (int mi = 0; mi < 4; ++mi) {
                int r = wm * 64 + mi * 16 + mrow;
                int s = ks * 4 + khalf;
                int ph = s ^ (r & 7);
                af[mi] = *(const f16x8*)(As + r * 64 + ph * 8);
            }
#pragma unroll
            for (int ni = 0; ni < 4; ++ni) {
                int r = wn * 64 + ni * 16 + mrow;
                int s = ks * 4 + khalf;
                int ph = s ^ (r & 7);
                bf[ni] = *(const f16x8*)(Bs + r * 64 + ph * 8);
            }
#pragma unroll
            for (int mi = 0; mi < 4; ++mi)
#pragma unroll
                for (int ni = 0; ni < 4; ++ni)
                    acc[mi][ni] = __builtin_amdgcn_mfma_f32_16x16x32_f16(
                        af[mi], bf[ni], acc[mi][ni], 0, 0, 0);
        }
    }
#pragma unroll
    for (int mi = 0; mi < 4; ++mi) {
#pragma unroll
        for (int r = 0; r < 4; ++r) {
            int row = brow + wm * 64 + mi * 16 + (lane >> 4) * 4 + r;
            if (row < M) {
#pragma unroll
                for (int ni = 0; ni < 4; ++ni) {
                    int colx = bcol + wn * 64 + ni * 16 + (lane & 15);
                    C[(size_t)row * Nn + colx] = (_Float16)acc[mi][ni][r];
                }
            }
        }
    }
}

// ------- batched fused two-relation gather + norm + bias + relu -----------
// grid (N, 2): side = blockIdx.y. F = blockDim.x.
__global__ void k_agg(const _Float16* __restrict__ Ya0, const _Float16* __restrict__ Yb0,
                      int ystride,
                      const int* __restrict__ row_ptr, const int* __restrict__ col,
                      const float* __restrict__ rs_out, const float* __restrict__ rs_in,
                      int ga0, int gb0,
                      const float* __restrict__ ba0, const float* __restrict__ bb0,
                      _Float16* __restrict__ outb, size_t out_sidestride, int ostride,
                      int N, int E) {
    int i = blockIdx.x, side = blockIdx.y;
    int f = threadIdx.x, F = blockDim.x;
    const _Float16* Ya = Ya0 + side * F;
    const _Float16* Yb = Yb0 + side * F;
    int ga = ga0 + side, gb = gb0 + side;
    float acc = ba0[side * F + f] + bb0[side * F + f];
    {
        const int* rp = row_ptr + (size_t)ga * (N + 1);
        const int* cg = col + (size_t)ga * E;
        const float* ro = rs_out + (size_t)ga * N;
        int beg = rp[i], end = rp[i + 1];
        float s = 0.0f;
        int sn = (beg < end) ? cg[beg] : 0;
        for (int e = beg; e < end; ++e) {
            int sn1 = (e + 1 < end) ? cg[e + 1] : 0;
            s += ro[sn] * (float)Ya[(size_t)sn * ystride + f];
            sn = sn1;
        }
        acc += rs_in[(size_t)ga * N + i] * s;
    }
    {
        const int* rp = row_ptr + (size_t)gb * (N + 1);
        const int* cg = col + (size_t)gb * E;
        const float* ro = rs_out + (size_t)gb * N;
        int beg = rp[i], end = rp[i + 1];
        float s = 0.0f;
        int sn = (beg < end) ? cg[beg] : 0;
        for (int e = beg; e < end; ++e) {
            int sn1 = (e + 1 < end) ? cg[e + 1] : 0;
            s += ro[sn] * (float)Yb[(size_t)sn * ystride + f];
            sn = sn1;
        }
        acc += rs_in[(size_t)gb * N + i] * s;
    }
    outb[side * out_sidestride + (size_t)i * ostride + f] = (_Float16)fmaxf(acc, 0.0f);
}

// ------- w reduction: w[m] = sum_f tanh(T[m][f]+bp[f])*q[f] ---------------
// T rows m = (side*N + node)*3 + k. One wave per row, 4 rows per block.
__global__ __launch_bounds__(256) void k_wred(const _Float16* __restrict__ T,
                                              const float* __restrict__ bp,
                                              const float* __restrict__ q,
                                              float* __restrict__ w_all, int N) {
    int m = blockIdx.x * 4 + (threadIdx.x >> 6);
    int lane = threadIdx.x & 63;
    if (m >= 6 * N) return;
    const _Float16* Tr = T + (size_t)m * 128;
    float v = tanhf((float)Tr[lane] + bp[lane]) * q[lane]
            + tanhf((float)Tr[lane + 64] + bp[lane + 64]) * q[lane + 64];
#pragma unroll
    for (int o = 1; o < 64; o <<= 1) v += __shfl_xor(v, o);
    if (lane == 0) {
        int side = m / (3 * N);
        int rem = m - side * 3 * N;
        int node = rem / 3, k = rem - node * 3;
        w_all[((size_t)side * 3 + k) * N + node] = v;
    }
}

// ---------------- beta: deterministic reduce + softmax --------------------
__global__ __launch_bounds__(256) void k_beta(const float* __restrict__ w_all,
                                              float* __restrict__ beta_ws,
                                              float* __restrict__ beta_out, int N) {
    int side = blockIdx.x;
    int tid = threadIdx.x;
    __shared__ float red[256];
    float sums[3];
    for (int k = 0; k < 3; ++k) {
        float s = 0.0f;
        for (int i = tid; i < N; i += 256) s += w_all[((size_t)side * 3 + k) * N + i];
        red[tid] = s;
        __syncthreads();
        for (int off = 128; off > 0; off >>= 1) {
            if (tid < off) red[tid] += red[tid + off];
            __syncthreads();
        }
        sums[k] = red[0];
        __syncthreads();
    }
    if (tid == 0) {
        float inv = 1.0f / (float)N;
        float m0 = sums[0] * inv, m1 = sums[1] * inv, m2 = sums[2] * inv;
        float mx = fmaxf(m0, fmaxf(m1, m2));
        float e0 = expf(m0 - mx), e1 = expf(m1 - mx), e2 = expf(m2 - mx);
        float denom = e0 + e1 + e2;
        float b0 = e0 / denom, b1 = e1 / denom, b2 = e2 / denom;
        beta_ws[side * 3 + 0] = b0; beta_out[side * 3 + 0] = b0;
        beta_ws[side * 3 + 1] = b1; beta_out[side * 3 + 1] = b1;
        beta_ws[side * 3 + 2] = b2; beta_out[side * 3 + 2] = b2;
    }
}

// ---------------- emb = sum_k beta[k] * z[:,k,:] (z fp16 -> out fp32) -----
__global__ __launch_bounds__(128) void k_emb(const _Float16* __restrict__ z,
                                             const float* __restrict__ beta_ws,
                                             float* __restrict__ out, int N) {
    int i = blockIdx.x, side = blockIdx.y, f = threadIdx.x;
    const _Float16* zr = z + (size_t)side * N * 384 + (size_t)i * 384;
    const float* b = beta_ws + side * 3;
    float v = b[0] * (float)zr[f] + b[1] * (float)zr[128 + f] + b[2] * (float)zr[256 + f];
    out[(size_t)side * N * 128 + (size_t)i * 128 + f] = v;
}

// ---------------------------------------------------------------------------
extern "C" void kernel_launch(void* const* d_in, const int* in_sizes, int n_in,
                              void* d_out, int out_size, void* d_ws, size_t ws_size,
                              hipStream_t stream) {
    const float* x_drug = (const float*)d_in[0];
    const float* x_pro  = (const float*)d_in[1];
    const int*   src    = (const int*)d_in[2];
    const int*   dst    = (const int*)d_in[3];
    const float* W1     = (const float*)d_in[4];
    const float* b1     = (const float*)d_in[5];
    const float* W2     = (const float*)d_in[6];
    const float* b2     = (const float*)d_in[7];
    const float* Wp     = (const float*)d_in[8];
    const float* bp     = (const float*)d_in[9];
    const float* q      = (const float*)d_in[10];
    float* out = (float*)d_out;

    const int N = in_sizes[0] / IN_F;      // 30000
    const int E = in_sizes[2] / 16;        // 250000

    size_t off = 0;
    auto alloc = [&](size_t bytes) -> void* {
        void* p = (char*)d_ws + off;
        off += (bytes + 255) & ~(size_t)255;
        return p;
    };
    int*      deg_in  = (int*)alloc((size_t)NG * N * 4);
    int*      row_ptr = (int*)alloc((size_t)NG * (N + 1) * 4);
    int*      col     = (int*)alloc((size_t)NG * E * 4);
    float*    rs_out  = (float*)alloc((size_t)NG * N * 4);
    float*    rs_in   = (float*)alloc((size_t)NG * N * 4);
    _Float16* xh      = (_Float16*)alloc((size_t)2 * N * IN_F * 2);          // [2][N][512]
    _Float16* W1cat   = (_Float16*)alloc((size_t)6 * 2 * HID_F * IN_F * 2);  // [6][512][512]
    _Float16* W2cat   = (_Float16*)alloc((size_t)6 * 2 * OUT_F * HID_F * 2); // [6][256][256]
    _Float16* WpT     = (_Float16*)alloc((size_t)128 * 128 * 2);
    _Float16* Y1      = (_Float16*)alloc((size_t)2 * N * 512 * 2);           // [2][N][512]
    _Float16* Y2      = (_Float16*)alloc((size_t)2 * N * 256 * 2);           // [2][N][256]
    _Float16* H1      = (_Float16*)alloc((size_t)2 * N * HID_F * 2);         // [2][N][256]
    _Float16* zbuf    = (_Float16*)alloc((size_t)2 * N * 384 * 2);           // [2][N][384]
    float*    w_all   = (float*)alloc((size_t)2 * 3 * N * 4);
    float*    beta_ws = (float*)alloc(64);
    _Float16* T       = Y1;   // reuse: Y1 (61 MB) dead after channel loop; T needs 46 MB
    (void)ws_size; (void)n_in; (void)out_size;

    // ---- CSR build ----
    dim3 pg(NG, NPART);
    k_deg2<<<pg, 512, 0, stream>>>(src, dst, deg_in, rs_out, rs_in, N, E);
    k_scan<<<NG, 1024, 0, stream>>>(deg_in, row_ptr, N);
    k_fill2<<<pg, 512, 0, stream>>>(src, dst, row_ptr, col, N, E);

    // ---- fp16 conversions ----
    size_t nx = (size_t)N * IN_F;
    k_cvt16<<<(int)((nx / 8 + 255) / 256), 256, 0, stream>>>(x_drug, xh, nx);
    k_cvt16<<<(int)((nx / 8 + 255) / 256), 256, 0, stream>>>(x_pro,  xh + nx, nx);
    k_cvtT<<<dim3(IN_F / 32, HID_F / 32, NG), 256, 0, stream>>>(W1, W1cat, IN_F, HID_F);
    k_cvtT<<<dim3(HID_F / 32, OUT_F / 32, NG), 256, 0, stream>>>(W2, W2cat, HID_F, OUT_F);
    k_cvtWp<<<dim3(4, 4), 256, 0, stream>>>(Wp, WpT);

    dim3 g1(512 / 128, (N + 127) / 128, 2);   // layer-1 GEMM: K=512, Nn=512, z=2
    dim3 g2(256 / 128, (N + 127) / 128, 2);   // layer-2 GEMM: K=256, Nn=256, z=2
    dim3 agrid(N, 2);

    for (int ci = 0; ci < 3; ++ci) {
        int c = chan_of(ci);
        // layer 1: z=0: xh_d @ [W1 c r0 | W1 c r1]; z=1: xh_p @ [W1 c r2 | W1 c r3]
        k_gemm16<<<g1, 256, 0, stream>>>(xh, (size_t)N * IN_F,
                                         W1cat + (size_t)ci * 2 * 512 * 512, (size_t)512 * 512,
                                         Y1, (size_t)N * 512,
                                         N, IN_F, 512);
        // L1 agg -> H1[side][N][256]
        k_agg<<<agrid, HID_F, 0, stream>>>(Y1, Y1 + (size_t)N * 512, 512,
                                           row_ptr, col, rs_out, rs_in,
                                           ci * 4 + 0, ci * 4 + 2,
                                           b1 + (size_t)c * 4 * HID_F, b1 + (size_t)(c * 4 + 2) * HID_F,
                                           H1, (size_t)N * HID_F, HID_F, N, E);
        // layer 2: z=0: H1d @ [W2 c r0 | W2 c r1]; z=1: H1p @ [W2 c r2 | W2 c r3]
        k_gemm16<<<g2, 256, 0, stream>>>(H1, (size_t)N * HID_F,
                                         W2cat + (size_t)ci * 2 * 256 * 256, (size_t)256 * 256,
                                         Y2, (size_t)N * 256,
                                         N, HID_F, 256);
        // L2 agg -> z[side][N][384] col block ci*128
        k_agg<<<agrid, OUT_F, 0, stream>>>(Y2, Y2 + (size_t)N * 256, 256,
                                           row_ptr, col, rs_out, rs_in,
                                           ci * 4 + 0, ci * 4 + 2,
                                           b2 + (size_t)c * 4 * OUT_F, b2 + (size_t)(c * 4 + 2) * OUT_F,
                                           zbuf + (size_t)ci * OUT_F, (size_t)N * 384, 384, N, E);
    }

    // ---- semantic attention: T = zbuf_flat[2N*3,128] @ WpT, then reduce ----
    int Mrows = 2 * N * 3;
    dim3 gT(1, (Mrows + 127) / 128, 1);
    k_gemm16<<<gT, 256, 0, stream>>>(zbuf, 0, WpT, 0, T, 0, Mrows, 128, 128);
    k_wred<<<(Mrows + 3) / 4, 256, 0, stream>>>(T, bp, q, w_all, N);
    k_beta<<<2, 256, 0, stream>>>(w_all, beta_ws, out + (size_t)2 * N * OUT_F, N);
    k_emb<<<agrid, OUT_F, 0, stream>>>(zbuf, beta_ws, out, N);
}

// Round 6
// 1374.142 us; speedup vs baseline: 2.7840x; 1.5122x over previous
//
#include <hip/hip_runtime.h>
#include <math.h>

// ---------------------------------------------------------------------------
// MCKRL round 6: CSR build restructured to edge-sliced atomic-free histograms
// (k_hist/k_rs2/k_fill3) - kills the 488-iteration serial edge scan that made
// k_deg2/k_fill2 latency-bound (238us each). k_agg/k_wred/k_emb vectorized to
// f16x2. hist slices overlay Y1 (dead until first GEMM). Rest as round 5.
// ---------------------------------------------------------------------------

#define IN_F  512
#define HID_F 256
#define OUT_F 128
#define NG    12       // 3 live channels x 4 relations
#define NPART 16
#define RANGE 1875     // 16*1875 = 30000
#define ES    8        // edge slices

typedef _Float16 f16x2 __attribute__((ext_vector_type(2)));
typedef _Float16 f16x8 __attribute__((ext_vector_type(8)));
typedef float    f32x4 __attribute__((ext_vector_type(4)));

#define AS1 __attribute__((address_space(1)))
#define AS3 __attribute__((address_space(3)))

__device__ __forceinline__ void gld16(const void* g, void* l) {
    __builtin_amdgcn_global_load_lds((const AS1 void*)g, (AS3 void*)l, 16, 0, 0);
}

__host__ __device__ __forceinline__ int chan_of(int ci) { return ci == 0 ? 0 : ci + 1; } // {0,2,3}

// ------- edge-sliced histograms: h[g][es][node], atomic-free global writes --
__global__ __launch_bounds__(512) void k_hist(const int* __restrict__ src,
                                              const int* __restrict__ dst,
                                              int* __restrict__ hin,
                                              int* __restrict__ hout,
                                              int N, int E) {
    __shared__ int hi[RANGE], ho[RANGE];
    int g = blockIdx.x, p = blockIdx.y, es = blockIdx.z, t = threadIdx.x;
    for (int i = t; i < RANGE; i += 512) { hi[i] = 0; ho[i] = 0; }
    __syncthreads();
    int ci = g >> 2, c = chan_of(ci), r = g & 3;
    const int* sp = src + (size_t)(c * 4 + r) * E;
    const int* dp = dst + (size_t)(c * 4 + r) * E;
    int lo = p * RANGE;
    int sl = E / ES;
    int e0 = es * sl, e1 = (es == ES - 1) ? E : e0 + sl;
    for (int e = e0 + t; e < e1; e += 512) {
        int s = sp[e] - lo;
        int d = dp[e] - lo;
        if ((unsigned)s < (unsigned)RANGE) atomicAdd(&ho[s], 1);
        if ((unsigned)d < (unsigned)RANGE) atomicAdd(&hi[d], 1);
    }
    __syncthreads();
    int* hing  = hin  + ((size_t)g * ES + es) * N;
    int* houtg = hout + ((size_t)g * ES + es) * N;
    for (int i = t; i < RANGE; i += 512) {
        int node = lo + i;
        if (node < N) { hing[node] = hi[i]; houtg[node] = ho[i]; }
    }
}

// ------- sum slices -> deg_in, rs_out, rs_in ------------------------------
__global__ void k_rs2(const int* __restrict__ hin, const int* __restrict__ hout,
                      int* __restrict__ deg_in,
                      float* __restrict__ rs_out, float* __restrict__ rs_in, int N) {
    int i = blockIdx.x * 256 + threadIdx.x;
    if (i >= NG * N) return;
    int g = i / N, n = i - g * N;
    int di = 0, dq = 0;
#pragma unroll
    for (int es = 0; es < ES; ++es) {
        di += hin [((size_t)g * ES + es) * N + n];
        dq += hout[((size_t)g * ES + es) * N + n];
    }
    deg_in[i] = di;
    rs_in[i]  = rsqrtf(fmaxf((float)di, 1.0f));
    rs_out[i] = rsqrtf(fmaxf((float)dq, 1.0f));
}

// ---------------- exclusive scan of deg_in -> row_ptr (shuffle) -----------
__global__ __launch_bounds__(1024) void k_scan(const int* __restrict__ deg_in,
                                               int* __restrict__ row_ptr, int N) {
    int g = blockIdx.x;
    const int* dg = deg_in + (size_t)g * N;
    int* rp = row_ptr + (size_t)g * (N + 1);
    __shared__ int wsum[16];
    int tid = threadIdx.x;
    int lane = tid & 63, wv = tid >> 6;
    int run = 0;
    for (int basei = 0; basei < N; basei += 1024) {
        int i = basei + tid;
        int v = (i < N) ? dg[i] : 0;
        int x = v;
#pragma unroll
        for (int off = 1; off < 64; off <<= 1) {
            int y = __shfl_up(x, off);
            if (lane >= off) x += y;
        }
        if (lane == 63) wsum[wv] = x;
        __syncthreads();
        if (wv == 0) {
            int s = (lane < 16) ? wsum[lane] : 0;
#pragma unroll
            for (int off = 1; off < 16; off <<= 1) {
                int y = __shfl_up(s, off);
                if (lane >= off) s += y;
            }
            if (lane < 16) wsum[lane] = s;
        }
        __syncthreads();
        int woff = wv ? wsum[wv - 1] : 0;
        if (i < N) rp[i] = run + woff + x - v;
        run += wsum[15];
        __syncthreads();
    }
    if (tid == 0) rp[N] = run;
}

// ------- CSR fill: edge-sliced, LDS cursors from row_ptr + slice prefix ---
__global__ __launch_bounds__(512) void k_fill3(const int* __restrict__ src,
                                               const int* __restrict__ dst,
                                               const int* __restrict__ row_ptr,
                                               const int* __restrict__ hin,
                                               int* __restrict__ col, int N, int E) {
    __shared__ int cur[RANGE];
    int g = blockIdx.x, p = blockIdx.y, es = blockIdx.z, t = threadIdx.x;
    int lo = p * RANGE;
    const int* rp = row_ptr + (size_t)g * (N + 1);
    for (int i = t; i < RANGE; i += 512) {
        int node = lo + i;
        int base = 0;
        if (node < N) {
            base = rp[node];
            for (int e2 = 0; e2 < es; ++e2)
                base += hin[((size_t)g * ES + e2) * N + node];
        }
        cur[i] = base;
    }
    __syncthreads();
    int ci = g >> 2, c = chan_of(ci), r = g & 3;
    const int* sp = src + (size_t)(c * 4 + r) * E;
    const int* dp = dst + (size_t)(c * 4 + r) * E;
    int* cg = col + (size_t)g * E;
    int sl = E / ES;
    int e0 = es * sl, e1 = (es == ES - 1) ? E : e0 + sl;
    for (int e = e0 + t; e < e1; e += 512) {
        int s = sp[e];
        int d = dp[e] - lo;
        if ((unsigned)d < (unsigned)RANGE) {
            int pos = atomicAdd(&cur[d], 1);
            cg[pos] = s;
        }
    }
}

// ---------------- fp32 -> fp16 elementwise (n multiple of 8) --------------
__global__ void k_cvt16(const float* __restrict__ in, _Float16* __restrict__ out,
                        size_t n) {
    size_t i = ((size_t)blockIdx.x * 256 + threadIdx.x) * 8;
    if (i >= n) return;
    float4 a = *(const float4*)(in + i);
    float4 b = *(const float4*)(in + i + 4);
    f16x8 v;
    v[0] = (_Float16)a.x; v[1] = (_Float16)a.y; v[2] = (_Float16)a.z; v[3] = (_Float16)a.w;
    v[4] = (_Float16)b.x; v[5] = (_Float16)b.y; v[6] = (_Float16)b.z; v[7] = (_Float16)b.w;
    *(f16x8*)(out + i) = v;
}

// ------- weight transpose+convert into concatenated f16 layout ------------
__global__ __launch_bounds__(256) void k_cvtT(const float* __restrict__ W,
                                              _Float16* __restrict__ out,
                                              int K, int Nn) {
    __shared__ float tile[32][33];
    int gi = blockIdx.z, ci = gi >> 2, c = chan_of(ci), r = gi & 3;
    const float* Wg = W + (size_t)(c * 4 + r) * K * Nn;
    _Float16* Wo = out + ((size_t)(ci * 2 + (r >> 1)) * 2 * Nn + (size_t)(r & 1) * Nn) * K;
    int k0 = blockIdx.x * 32, n0 = blockIdx.y * 32;
    int tx = threadIdx.x & 31, ty = threadIdx.x >> 5;   // 32 x 8
    for (int yy = ty; yy < 32; yy += 8)
        tile[yy][tx] = Wg[(size_t)(k0 + yy) * Nn + n0 + tx];
    __syncthreads();
    for (int yy = ty; yy < 32; yy += 8)
        Wo[(size_t)(n0 + yy) * K + k0 + tx] = (_Float16)tile[tx][yy];
}

// ------- Wp [128][128] f32 -> WpT [n][k] f16 ------------------------------
__global__ __launch_bounds__(256) void k_cvtWp(const float* __restrict__ Wp,
                                               _Float16* __restrict__ WpT) {
    __shared__ float tile[32][33];
    int k0 = blockIdx.x * 32, n0 = blockIdx.y * 32;
    int tx = threadIdx.x & 31, ty = threadIdx.x >> 5;
    for (int yy = ty; yy < 32; yy += 8)
        tile[yy][tx] = Wp[(size_t)(k0 + yy) * 128 + n0 + tx];
    __syncthreads();
    for (int yy = ty; yy < 32; yy += 8)
        WpT[(size_t)(n0 + yy) * 128 + k0 + tx] = (_Float16)tile[tx][yy];
}

// ---------------- z-batched fp16 MFMA GEMM: C = A @ Bt^T ------------------
// 128x128 tile, BK=64, 256 threads (4 waves 2x2), 16x16x32_f16 MFMA.
__global__ __launch_bounds__(256) void k_gemm16(const _Float16* __restrict__ A0, size_t Azs,
                                                const _Float16* __restrict__ B0, size_t Bzs,
                                                _Float16* __restrict__ C0, size_t Czs,
                                                int M, int K, int Nn) {
    const _Float16* A = A0 + (size_t)blockIdx.z * Azs;
    const _Float16* Bt = B0 + (size_t)blockIdx.z * Bzs;
    _Float16* C = C0 + (size_t)blockIdx.z * Czs;
    __shared__ __align__(16) _Float16 As[128 * 64];
    __shared__ __align__(16) _Float16 Bs[128 * 64];
    int t = threadIdx.x;
    int lane = t & 63, wid = t >> 6;
    int wm = wid >> 1, wn = wid & 1;
    int brow = blockIdx.y * 128, bcol = blockIdx.x * 128;

    f32x4 acc[4][4] = {};
    int mrow = lane & 15;
    int khalf = lane >> 4;   // 0..3

    for (int k0 = 0; k0 < K; k0 += 64) {
        __syncthreads();
#pragma unroll
        for (int i = 0; i < 4; ++i) {
            int L = t + i * 256;
            int row = L >> 3, spp = L & 7;
            int sg = spp ^ (row & 7);           // pre-swizzled global slot
            int ra = brow + row; if (ra > M - 1) ra = M - 1;
            gld16((const void*)(A + (size_t)ra * K + (size_t)(k0 + sg * 8)),
                  (void*)(As + (size_t)(i * 256 + wid * 64) * 8));
            int rb = bcol + row;
            gld16((const void*)(Bt + (size_t)rb * K + (size_t)(k0 + sg * 8)),
                  (void*)(Bs + (size_t)(i * 256 + wid * 64) * 8));
        }
        __syncthreads();
#pragma unroll
        for (int ks = 0; ks < 2; ++ks) {
            f16x8 af[4], bf[4];
#pragma unroll
            for (int mi = 0; mi < 4; ++mi) {
                int r = wm * 64 + mi * 16 + mrow;
                int s = ks * 4 + khalf;
                int ph = s ^ (r & 7);
                af[mi] = *(const f16x8*)(As + r * 64 + ph * 8);
            }
#pragma unroll
            for (int ni = 0; ni < 4; ++ni) {
                int r = wn * 64 + ni * 16 + mrow;
                int s = ks * 4 + khalf;
                int ph = s ^ (r & 7);
                bf[ni] = *(const f16x8*)(Bs + r * 64 + ph * 8);
            }
#pragma unroll
            for (int mi = 0; mi < 4; ++mi)
#pragma unroll
                for (int ni = 0; ni < 4; ++ni)
                    acc[mi][ni] = __builtin_amdgcn_mfma_f32_16x16x32_f16(
                        af[mi], bf[ni], acc[mi][ni], 0, 0, 0);
        }
    }
#pragma unroll
    for (int mi = 0; mi < 4; ++mi) {
#pragma unroll
        for (int r = 0; r < 4; ++r) {
            int row = brow + wm * 64 + mi * 16 + (lane >> 4) * 4 + r;
            if (row < M) {
#pragma unroll
                for (int ni = 0; ni < 4; ++ni) {
                    int colx = bcol + wn * 64 + ni * 16 + (lane & 15);
                    C[(size_t)row * Nn + colx] = (_Float16)acc[mi][ni][r];
                }
            }
        }
    }
}

// ------- batched fused two-relation gather + norm + bias + relu (f16x2) ---
// grid (N, 2): side = blockIdx.y. blockDim.x = F/2.
__global__ void k_agg2(const _Float16* __restrict__ Ya0, const _Float16* __restrict__ Yb0,
                       int ystride,
                       const int* __restrict__ row_ptr, const int* __restrict__ col,
                       const float* __restrict__ rs_out, const float* __restrict__ rs_in,
                       int ga0, int gb0,
                       const float* __restrict__ ba0, const float* __restrict__ bb0,
                       _Float16* __restrict__ outb, size_t out_sidestride, int ostride,
                       int F, int N, int E) {
    int i = blockIdx.x, side = blockIdx.y;
    int f0 = 2 * threadIdx.x;
    const _Float16* Ya = Ya0 + side * F;
    const _Float16* Yb = Yb0 + side * F;
    int ga = ga0 + side, gb = gb0 + side;
    float a0 = ba0[side * F + f0] + bb0[side * F + f0];
    float a1 = ba0[side * F + f0 + 1] + bb0[side * F + f0 + 1];
    {
        const int* rp = row_ptr + (size_t)ga * (N + 1);
        const int* cg = col + (size_t)ga * E;
        const float* ro = rs_out + (size_t)ga * N;
        int beg = rp[i], end = rp[i + 1];
        float s0 = 0.0f, s1 = 0.0f;
        int sn = (beg < end) ? cg[beg] : 0;
        for (int e = beg; e < end; ++e) {
            int sn1 = (e + 1 < end) ? cg[e + 1] : 0;
            f16x2 v = *(const f16x2*)(Ya + (size_t)sn * ystride + f0);
            float w = ro[sn];
            s0 = fmaf(w, (float)v[0], s0);
            s1 = fmaf(w, (float)v[1], s1);
            sn = sn1;
        }
        float ri = rs_in[(size_t)ga * N + i];
        a0 = fmaf(ri, s0, a0); a1 = fmaf(ri, s1, a1);
    }
    {
        const int* rp = row_ptr + (size_t)gb * (N + 1);
        const int* cg = col + (size_t)gb * E;
        const float* ro = rs_out + (size_t)gb * N;
        int beg = rp[i], end = rp[i + 1];
        float s0 = 0.0f, s1 = 0.0f;
        int sn = (beg < end) ? cg[beg] : 0;
        for (int e = beg; e < end; ++e) {
            int sn1 = (e + 1 < end) ? cg[e + 1] : 0;
            f16x2 v = *(const f16x2*)(Yb + (size_t)sn * ystride + f0);
            float w = ro[sn];
            s0 = fmaf(w, (float)v[0], s0);
            s1 = fmaf(w, (float)v[1], s1);
            sn = sn1;
        }
        float ri = rs_in[(size_t)gb * N + i];
        a0 = fmaf(ri, s0, a0); a1 = fmaf(ri, s1, a1);
    }
    f16x2 o;
    o[0] = (_Float16)fmaxf(a0, 0.0f);
    o[1] = (_Float16)fmaxf(a1, 0.0f);
    *(f16x2*)(outb + side * out_sidestride + (size_t)i * ostride + f0) = o;
}

// ------- w reduction: w[m] = sum_f tanh(T[m][f]+bp[f])*q[f] ---------------
__global__ __launch_bounds__(256) void k_wred(const _Float16* __restrict__ T,
                                              const float* __restrict__ bp,
                                              const float* __restrict__ q,
                                              float* __restrict__ w_all, int N) {
    int m = blockIdx.x * 4 + (threadIdx.x >> 6);
    int lane = threadIdx.x & 63;
    if (m >= 6 * N) return;
    f16x2 v2 = *(const f16x2*)(T + (size_t)m * 128 + 2 * lane);
    float v = tanhf((float)v2[0] + bp[2 * lane]) * q[2 * lane]
            + tanhf((float)v2[1] + bp[2 * lane + 1]) * q[2 * lane + 1];
#pragma unroll
    for (int o = 1; o < 64; o <<= 1) v += __shfl_xor(v, o);
    if (lane == 0) {
        int side = m / (3 * N);
        int rem = m - side * 3 * N;
        int node = rem / 3, k = rem - node * 3;
        w_all[((size_t)side * 3 + k) * N + node] = v;
    }
}

// ---------------- beta: deterministic reduce + softmax --------------------
__global__ __launch_bounds__(256) void k_beta(const float* __restrict__ w_all,
                                              float* __restrict__ beta_ws,
                                              float* __restrict__ beta_out, int N) {
    int side = blockIdx.x;
    int tid = threadIdx.x;
    __shared__ float red[256];
    float sums[3];
    for (int k = 0; k < 3; ++k) {
        float s = 0.0f;
        for (int i = tid; i < N; i += 256) s += w_all[((size_t)side * 3 + k) * N + i];
        red[tid] = s;
        __syncthreads();
        for (int off = 128; off > 0; off >>= 1) {
            if (tid < off) red[tid] += red[tid + off];
            __syncthreads();
        }
        sums[k] = red[0];
        __syncthreads();
    }
    if (tid == 0) {
        float inv = 1.0f / (float)N;
        float m0 = sums[0] * inv, m1 = sums[1] * inv, m2 = sums[2] * inv;
        float mx = fmaxf(m0, fmaxf(m1, m2));
        float e0 = expf(m0 - mx), e1 = expf(m1 - mx), e2 = expf(m2 - mx);
        float denom = e0 + e1 + e2;
        float b0 = e0 / denom, b1 = e1 / denom, b2 = e2 / denom;
        beta_ws[side * 3 + 0] = b0; beta_out[side * 3 + 0] = b0;
        beta_ws[side * 3 + 1] = b1; beta_out[side * 3 + 1] = b1;
        beta_ws[side * 3 + 2] = b2; beta_out[side * 3 + 2] = b2;
    }
}

// ---------------- emb = sum_k beta[k] * z[:,k,:] (f16x2) ------------------
__global__ __launch_bounds__(64) void k_emb(const _Float16* __restrict__ z,
                                            const float* __restrict__ beta_ws,
                                            float* __restrict__ out, int N) {
    int i = blockIdx.x, side = blockIdx.y, t = threadIdx.x;
    const _Float16* zr = z + (size_t)side * N * 384 + (size_t)i * 384;
    const float* b = beta_ws + side * 3;
    f16x2 z0 = *(const f16x2*)(zr + 2 * t);
    f16x2 z1 = *(const f16x2*)(zr + 128 + 2 * t);
    f16x2 z2 = *(const f16x2*)(zr + 256 + 2 * t);
    float2 o;
    o.x = b[0] * (float)z0[0] + b[1] * (float)z1[0] + b[2] * (float)z2[0];
    o.y = b[0] * (float)z0[1] + b[1] * (float)z1[1] + b[2] * (float)z2[1];
    *(float2*)&out[(size_t)side * N * 128 + (size_t)i * 128 + 2 * t] = o;
}

// ---------------------------------------------------------------------------
extern "C" void kernel_launch(void* const* d_in, const int* in_sizes, int n_in,
                              void* d_out, int out_size, void* d_ws, size_t ws_size,
                              hipStream_t stream) {
    const float* x_drug = (const float*)d_in[0];
    const float* x_pro  = (const float*)d_in[1];
    const int*   src    = (const int*)d_in[2];
    const int*   dst    = (const int*)d_in[3];
    const float* W1     = (const float*)d_in[4];
    const float* b1     = (const float*)d_in[5];
    const float* W2     = (const float*)d_in[6];
    const float* b2     = (const float*)d_in[7];
    const float* Wp     = (const float*)d_in[8];
    const float* bp     = (const float*)d_in[9];
    const float* q      = (const float*)d_in[10];
    float* out = (float*)d_out;

    const int N = in_sizes[0] / IN_F;      // 30000
    const int E = in_sizes[2] / 16;        // 250000

    size_t off = 0;
    auto alloc = [&](size_t bytes) -> void* {
        void* p = (char*)d_ws + off;
        off += (bytes + 255) & ~(size_t)255;
        return p;
    };
    int*      deg_in  = (int*)alloc((size_t)NG * N * 4);
    int*      row_ptr = (int*)alloc((size_t)NG * (N + 1) * 4);
    int*      col     = (int*)alloc((size_t)NG * E * 4);
    float*    rs_out  = (float*)alloc((size_t)NG * N * 4);
    float*    rs_in   = (float*)alloc((size_t)NG * N * 4);
    _Float16* xh      = (_Float16*)alloc((size_t)2 * N * IN_F * 2);          // [2][N][512]
    _Float16* W1cat   = (_Float16*)alloc((size_t)6 * 2 * HID_F * IN_F * 2);  // [6][512][512]
    _Float16* W2cat   = (_Float16*)alloc((size_t)6 * 2 * OUT_F * HID_F * 2); // [6][256][256]
    _Float16* WpT     = (_Float16*)alloc((size_t)128 * 128 * 2);
    _Float16* Y1      = (_Float16*)alloc((size_t)2 * N * 512 * 2);           // [2][N][512]
    _Float16* Y2      = (_Float16*)alloc((size_t)2 * N * 256 * 2);           // [2][N][256]
    _Float16* H1      = (_Float16*)alloc((size_t)2 * N * HID_F * 2);         // [2][N][256]
    _Float16* zbuf    = (_Float16*)alloc((size_t)2 * N * 384 * 2);           // [2][N][384]
    float*    w_all   = (float*)alloc((size_t)2 * 3 * N * 4);
    float*    beta_ws = (float*)alloc(64);
    // Overlays into Y1 (61.4 MB): hist slices (23 MB, dead before first GEMM)
    // and attention T (46 MB, after hists are dead).
    int*      hin  = (int*)Y1;                       // [NG][ES][N]
    int*      hout = hin + (size_t)NG * ES * N;      // [NG][ES][N]
    _Float16* T    = Y1;
    (void)ws_size; (void)n_in; (void)out_size;

    // ---- CSR build (edge-sliced, atomic-free hist) ----
    dim3 hg(NG, NPART, ES);
    k_hist<<<hg, 512, 0, stream>>>(src, dst, hin, hout, N, E);
    k_rs2<<<(NG * N + 255) / 256, 256, 0, stream>>>(hin, hout, deg_in, rs_out, rs_in, N);
    k_scan<<<NG, 1024, 0, stream>>>(deg_in, row_ptr, N);
    k_fill3<<<hg, 512, 0, stream>>>(src, dst, row_ptr, hin, col, N, E);

    // ---- fp16 conversions ----
    size_t nx = (size_t)N * IN_F;
    k_cvt16<<<(int)((nx / 8 + 255) / 256), 256, 0, stream>>>(x_drug, xh, nx);
    k_cvt16<<<(int)((nx / 8 + 255) / 256), 256, 0, stream>>>(x_pro,  xh + nx, nx);
    k_cvtT<<<dim3(IN_F / 32, HID_F / 32, NG), 256, 0, stream>>>(W1, W1cat, IN_F, HID_F);
    k_cvtT<<<dim3(HID_F / 32, OUT_F / 32, NG), 256, 0, stream>>>(W2, W2cat, HID_F, OUT_F);
    k_cvtWp<<<dim3(4, 4), 256, 0, stream>>>(Wp, WpT);

    dim3 g1(512 / 128, (N + 127) / 128, 2);   // layer-1 GEMM: K=512, Nn=512, z=2
    dim3 g2(256 / 128, (N + 127) / 128, 2);   // layer-2 GEMM: K=256, Nn=256, z=2
    dim3 agrid(N, 2);

    for (int ci = 0; ci < 3; ++ci) {
        int c = chan_of(ci);
        // layer 1: z=0: xh_d @ [W1 c r0 | W1 c r1]; z=1: xh_p @ [W1 c r2 | W1 c r3]
        k_gemm16<<<g1, 256, 0, stream>>>(xh, (size_t)N * IN_F,
                                         W1cat + (size_t)ci * 2 * 512 * 512, (size_t)512 * 512,
                                         Y1, (size_t)N * 512,
                                         N, IN_F, 512);
        // L1 agg -> H1[side][N][256]
        k_agg2<<<agrid, HID_F / 2, 0, stream>>>(Y1, Y1 + (size_t)N * 512, 512,
                                                row_ptr, col, rs_out, rs_in,
                                                ci * 4 + 0, ci * 4 + 2,
                                                b1 + (size_t)c * 4 * HID_F, b1 + (size_t)(c * 4 + 2) * HID_F,
                                                H1, (size_t)N * HID_F, HID_F, HID_F, N, E);
        // layer 2: z=0: H1d @ [W2 c r0 | W2 c r1]; z=1: H1p @ [W2 c r2 | W2 c r3]
        k_gemm16<<<g2, 256, 0, stream>>>(H1, (size_t)N * HID_F,
                                         W2cat + (size_t)ci * 2 * 256 * 256, (size_t)256 * 256,
                                         Y2, (size_t)N * 256,
                                         N, HID_F, 256);
        // L2 agg -> z[side][N][384] col block ci*128
        k_agg2<<<agrid, OUT_F / 2, 0, stream>>>(Y2, Y2 + (size_t)N * 256, 256,
                                                row_ptr, col, rs_out, rs_in,
                                                ci * 4 + 0, ci * 4 + 2,
                                                b2 + (size_t)c * 4 * OUT_F, b2 + (size_t)(c * 4 + 2) * OUT_F,
                                                zbuf + (size_t)ci * OUT_F, (size_t)N * 384, 384, OUT_F, N, E);
    }

    // ---- semantic attention: T = zbuf_flat[2N*3,128] @ WpT, then reduce ----
    int Mrows = 2 * N * 3;
    dim3 gT(1, (Mrows + 127) / 128, 1);
    k_gemm16<<<gT, 256, 0, stream>>>(zbuf, 0, WpT, 0, T, 0, Mrows, 128, 128);
    k_wred<<<(Mrows + 3) / 4, 256, 0, stream>>>(T, bp, q, w_all, N);
    k_beta<<<2, 256, 0, stream>>>(w_all, beta_ws, out + (size_t)2 * N * OUT_F, N);
    k_emb<<<agrid, 64, 0, stream>>>(zbuf, beta_ws, out, N);
}

// Round 7
// 1215.548 us; speedup vs baseline: 3.1473x; 1.1305x over previous
//
#include <hip/hip_runtime.h>
#include <math.h>

// ---------------------------------------------------------------------------
// MCKRL round 7: gather MLP fix - one wave per node (f16x4/f16x2 row loads),
// 4-deep unrolled edge loop (4 outstanding 512B requests/wave vs 1), rs_out
// folded into GEMM epilogue (kills per-edge random 4B load). CSR build,
// GEMM structure, attention path as round 6.
// ---------------------------------------------------------------------------

#define IN_F  512
#define HID_F 256
#define OUT_F 128
#define NG    12       // 3 live channels x 4 relations
#define NPART 16
#define RANGE 1875     // 16*1875 = 30000
#define ES    8        // edge slices

typedef _Float16 f16x2 __attribute__((ext_vector_type(2)));
typedef _Float16 f16x4 __attribute__((ext_vector_type(4)));
typedef _Float16 f16x8 __attribute__((ext_vector_type(8)));
typedef float    f32x4 __attribute__((ext_vector_type(4)));

#define AS1 __attribute__((address_space(1)))
#define AS3 __attribute__((address_space(3)))

__device__ __forceinline__ void gld16(const void* g, void* l) {
    __builtin_amdgcn_global_load_lds((const AS1 void*)g, (AS3 void*)l, 16, 0, 0);
}

__host__ __device__ __forceinline__ int chan_of(int ci) { return ci == 0 ? 0 : ci + 1; } // {0,2,3}

// ------- edge-sliced histograms: h[g][es][node], atomic-free global writes --
__global__ __launch_bounds__(512) void k_hist(const int* __restrict__ src,
                                              const int* __restrict__ dst,
                                              int* __restrict__ hin,
                                              int* __restrict__ hout,
                                              int N, int E) {
    __shared__ int hi[RANGE], ho[RANGE];
    int g = blockIdx.x, p = blockIdx.y, es = blockIdx.z, t = threadIdx.x;
    for (int i = t; i < RANGE; i += 512) { hi[i] = 0; ho[i] = 0; }
    __syncthreads();
    int ci = g >> 2, c = chan_of(ci), r = g & 3;
    const int* sp = src + (size_t)(c * 4 + r) * E;
    const int* dp = dst + (size_t)(c * 4 + r) * E;
    int lo = p * RANGE;
    int sl = E / ES;
    int e0 = es * sl, e1 = (es == ES - 1) ? E : e0 + sl;
    for (int e = e0 + t; e < e1; e += 512) {
        int s = sp[e] - lo;
        int d = dp[e] - lo;
        if ((unsigned)s < (unsigned)RANGE) atomicAdd(&ho[s], 1);
        if ((unsigned)d < (unsigned)RANGE) atomicAdd(&hi[d], 1);
    }
    __syncthreads();
    int* hing  = hin  + ((size_t)g * ES + es) * N;
    int* houtg = hout + ((size_t)g * ES + es) * N;
    for (int i = t; i < RANGE; i += 512) {
        int node = lo + i;
        if (node < N) { hing[node] = hi[i]; houtg[node] = ho[i]; }
    }
}

// ------- sum slices -> deg_in, rs_out, rs_in ------------------------------
__global__ void k_rs2(const int* __restrict__ hin, const int* __restrict__ hout,
                      int* __restrict__ deg_in,
                      float* __restrict__ rs_out, float* __restrict__ rs_in, int N) {
    int i = blockIdx.x * 256 + threadIdx.x;
    if (i >= NG * N) return;
    int g = i / N, n = i - g * N;
    int di = 0, dq = 0;
#pragma unroll
    for (int es = 0; es < ES; ++es) {
        di += hin [((size_t)g * ES + es) * N + n];
        dq += hout[((size_t)g * ES + es) * N + n];
    }
    deg_in[i] = di;
    rs_in[i]  = rsqrtf(fmaxf((float)di, 1.0f));
    rs_out[i] = rsqrtf(fmaxf((float)dq, 1.0f));
}

// ---------------- exclusive scan of deg_in -> row_ptr (shuffle) -----------
__global__ __launch_bounds__(1024) void k_scan(const int* __restrict__ deg_in,
                                               int* __restrict__ row_ptr, int N) {
    int g = blockIdx.x;
    const int* dg = deg_in + (size_t)g * N;
    int* rp = row_ptr + (size_t)g * (N + 1);
    __shared__ int wsum[16];
    int tid = threadIdx.x;
    int lane = tid & 63, wv = tid >> 6;
    int run = 0;
    for (int basei = 0; basei < N; basei += 1024) {
        int i = basei + tid;
        int v = (i < N) ? dg[i] : 0;
        int x = v;
#pragma unroll
        for (int off = 1; off < 64; off <<= 1) {
            int y = __shfl_up(x, off);
            if (lane >= off) x += y;
        }
        if (lane == 63) wsum[wv] = x;
        __syncthreads();
        if (wv == 0) {
            int s = (lane < 16) ? wsum[lane] : 0;
#pragma unroll
            for (int off = 1; off < 16; off <<= 1) {
                int y = __shfl_up(s, off);
                if (lane >= off) s += y;
            }
            if (lane < 16) wsum[lane] = s;
        }
        __syncthreads();
        int woff = wv ? wsum[wv - 1] : 0;
        if (i < N) rp[i] = run + woff + x - v;
        run += wsum[15];
        __syncthreads();
    }
    if (tid == 0) rp[N] = run;
}

// ------- CSR fill: edge-sliced, LDS cursors from row_ptr + slice prefix ---
__global__ __launch_bounds__(512) void k_fill3(const int* __restrict__ src,
                                               const int* __restrict__ dst,
                                               const int* __restrict__ row_ptr,
                                               const int* __restrict__ hin,
                                               int* __restrict__ col, int N, int E) {
    __shared__ int cur[RANGE];
    int g = blockIdx.x, p = blockIdx.y, es = blockIdx.z, t = threadIdx.x;
    int lo = p * RANGE;
    const int* rp = row_ptr + (size_t)g * (N + 1);
    for (int i = t; i < RANGE; i += 512) {
        int node = lo + i;
        int base = 0;
        if (node < N) {
            base = rp[node];
            for (int e2 = 0; e2 < es; ++e2)
                base += hin[((size_t)g * ES + e2) * N + node];
        }
        cur[i] = base;
    }
    __syncthreads();
    int ci = g >> 2, c = chan_of(ci), r = g & 3;
    const int* sp = src + (size_t)(c * 4 + r) * E;
    const int* dp = dst + (size_t)(c * 4 + r) * E;
    int* cg = col + (size_t)g * E;
    int sl = E / ES;
    int e0 = es * sl, e1 = (es == ES - 1) ? E : e0 + sl;
    for (int e = e0 + t; e < e1; e += 512) {
        int s = sp[e];
        int d = dp[e] - lo;
        if ((unsigned)d < (unsigned)RANGE) {
            int pos = atomicAdd(&cur[d], 1);
            cg[pos] = s;
        }
    }
}

// ---------------- fp32 -> fp16 elementwise (n multiple of 8) --------------
__global__ void k_cvt16(const float* __restrict__ in, _Float16* __restrict__ out,
                        size_t n) {
    size_t i = ((size_t)blockIdx.x * 256 + threadIdx.x) * 8;
    if (i >= n) return;
    float4 a = *(const float4*)(in + i);
    float4 b = *(const float4*)(in + i + 4);
    f16x8 v;
    v[0] = (_Float16)a.x; v[1] = (_Float16)a.y; v[2] = (_Float16)a.z; v[3] = (_Float16)a.w;
    v[4] = (_Float16)b.x; v[5] = (_Float16)b.y; v[6] = (_Float16)b.z; v[7] = (_Float16)b.w;
    *(f16x8*)(out + i) = v;
}

// ------- weight transpose+convert into concatenated f16 layout ------------
__global__ __launch_bounds__(256) void k_cvtT(const float* __restrict__ W,
                                              _Float16* __restrict__ out,
                                              int K, int Nn) {
    __shared__ float tile[32][33];
    int gi = blockIdx.z, ci = gi >> 2, c = chan_of(ci), r = gi & 3;
    const float* Wg = W + (size_t)(c * 4 + r) * K * Nn;
    _Float16* Wo = out + ((size_t)(ci * 2 + (r >> 1)) * 2 * Nn + (size_t)(r & 1) * Nn) * K;
    int k0 = blockIdx.x * 32, n0 = blockIdx.y * 32;
    int tx = threadIdx.x & 31, ty = threadIdx.x >> 5;   // 32 x 8
    for (int yy = ty; yy < 32; yy += 8)
        tile[yy][tx] = Wg[(size_t)(k0 + yy) * Nn + n0 + tx];
    __syncthreads();
    for (int yy = ty; yy < 32; yy += 8)
        Wo[(size_t)(n0 + yy) * K + k0 + tx] = (_Float16)tile[tx][yy];
}

// ------- Wp [128][128] f32 -> WpT [n][k] f16 ------------------------------
__global__ __launch_bounds__(256) void k_cvtWp(const float* __restrict__ Wp,
                                               _Float16* __restrict__ WpT) {
    __shared__ float tile[32][33];
    int k0 = blockIdx.x * 32, n0 = blockIdx.y * 32;
    int tx = threadIdx.x & 31, ty = threadIdx.x >> 5;
    for (int yy = ty; yy < 32; yy += 8)
        tile[yy][tx] = Wp[(size_t)(k0 + yy) * 128 + n0 + tx];
    __syncthreads();
    for (int yy = ty; yy < 32; yy += 8)
        WpT[(size_t)(n0 + yy) * 128 + k0 + tx] = (_Float16)tile[tx][yy];
}

// ---------------- z-batched fp16 MFMA GEMM: C = A @ Bt^T ------------------
// 128x128 tile, BK=64, 256 threads (4 waves 2x2), 16x16x32_f16 MFMA.
// Epilogue folds per-source-row rs_out scaling: scale = rs0[2z*rsN + row]
// for col < Nsplit else rs0[(2z+1)*rsN + row]; rs0==null -> no scaling.
__global__ __launch_bounds__(256) void k_gemm16(const _Float16* __restrict__ A0, size_t Azs,
                                                const _Float16* __restrict__ B0, size_t Bzs,
                                                _Float16* __restrict__ C0, size_t Czs,
                                                const float* __restrict__ rs0, int rsN,
                                                int Nsplit,
                                                int M, int K, int Nn) {
    const _Float16* A = A0 + (size_t)blockIdx.z * Azs;
    const _Float16* Bt = B0 + (size_t)blockIdx.z * Bzs;
    _Float16* C = C0 + (size_t)blockIdx.z * Czs;
    const float* rsA = rs0 ? rs0 + (size_t)(2 * blockIdx.z) * rsN : nullptr;
    __shared__ __align__(16) _Float16 As[128 * 64];
    __shared__ __align__(16) _Float16 Bs[128 * 64];
    int t = threadIdx.x;
    int lane = t & 63, wid = t >> 6;
    int wm = wid >> 1, wn = wid & 1;
    int brow = blockIdx.y * 128, bcol = blockIdx.x * 128;

    f32x4 acc[4][4] = {};
    int mrow = lane & 15;
    int khalf = lane >> 4;   // 0..3

    for (int k0 = 0; k0 < K; k0 += 64) {
        __syncthreads();
#pragma unroll
        for (int i = 0; i < 4; ++i) {
            int L = t + i * 256;
            int row = L >> 3, spp = L & 7;
            int sg = spp ^ (row & 7);           // pre-swizzled global slot
            int ra = brow + row; if (ra > M - 1) ra = M - 1;
            gld16((const void*)(A + (size_t)ra * K + (size_t)(k0 + sg * 8)),
                  (void*)(As + (size_t)(i * 256 + wid * 64) * 8));
            int rb = bcol + row;
            gld16((const void*)(Bt + (size_t)rb * K + (size_t)(k0 + sg * 8)),
                  (void*)(Bs + (size_t)(i * 256 + wid * 64) * 8));
        }
        __syncthreads();
#pragma unroll
        for (int ks = 0; ks < 2; ++ks) {
            f16x8 af[4], bf[4];
#pragma unroll
            for (int mi = 0; mi < 4; ++mi) {
                int r = wm * 64 + mi * 16 + mrow;
                int s = ks * 4 + khalf;
                int ph = s ^ (r & 7);
                af[mi] = *(const f16x8*)(As + r * 64 + ph * 8);
            }
#pragma unroll
            for (int ni = 0; ni < 4; ++ni) {
                int r = wn * 64 + ni * 16 + mrow;
                int s = ks * 4 + khalf;
                int ph = s ^ (r & 7);
                bf[ni] = *(const f16x8*)(Bs + r * 64 + ph * 8);
            }
#pragma unroll
            for (int mi = 0; mi < 4; ++mi)
#pragma unroll
                for (int ni = 0; ni < 4; ++ni)
                    acc[mi][ni] = __builtin_amdgcn_mfma_f32_16x16x32_f16(
                        af[mi], bf[ni], acc[mi][ni], 0, 0, 0);
        }
    }
#pragma unroll
    for (int mi = 0; mi < 4; ++mi) {
#pragma unroll
        for (int r = 0; r < 4; ++r) {
            int row = brow + wm * 64 + mi * 16 + (lane >> 4) * 4 + r;
            if (row < M) {
                float sA = 1.0f, sB = 1.0f;
                if (rsA) { sA = rsA[row]; sB = rsA[rsN + row]; }
#pragma unroll
                for (int ni = 0; ni < 4; ++ni) {
                    int colx = bcol + wn * 64 + ni * 16 + (lane & 15);
                    float sc = (colx < Nsplit) ? sA : sB;
                    C[(size_t)row * Nn + colx] = (_Float16)(acc[mi][ni][r] * sc);
                }
            }
        }
    }
}

// ------- gather: one wave per node, 4-deep unrolled edge loop -------------
// Y rows already rs_out-scaled (GEMM epilogue). VEC = F/64 halves per lane.
template<typename FV, int VEC>
__device__ __forceinline__ void agg_body(const _Float16* __restrict__ Ya0,
                                         const _Float16* __restrict__ Yb0, int ystride,
                                         const int* __restrict__ row_ptr,
                                         const int* __restrict__ col,
                                         const float* __restrict__ rs_in,
                                         int ga0, int gb0,
                                         const float* __restrict__ ba0,
                                         const float* __restrict__ bb0,
                                         _Float16* __restrict__ outb,
                                         size_t out_sidestride, int ostride,
                                         int F, int N, int E) {
    int wv = threadIdx.x >> 6, lane = threadIdx.x & 63;
    int i = blockIdx.x * 4 + wv;
    if (i >= N) return;
    int side = blockIdx.y;
    int f0 = VEC * lane;
    const _Float16* Ya = Ya0 + side * F;
    const _Float16* Yb = Yb0 + side * F;
    int ga = ga0 + side, gb = gb0 + side;

    float accA[VEC] = {}, accB[VEC] = {};
    {
        const int* rp = row_ptr + (size_t)ga * (N + 1);
        const int* cg = col + (size_t)ga * E;
        int beg = rp[i], end = rp[i + 1];
        for (int e = beg; e < end; e += 4) {
            int s0 = cg[e];
            bool b1 = e + 1 < end, b2 = e + 2 < end, b3 = e + 3 < end;
            int s1 = b1 ? cg[e + 1] : s0;
            int s2 = b2 ? cg[e + 2] : s0;
            int s3 = b3 ? cg[e + 3] : s0;
            FV v0 = *(const FV*)(Ya + (size_t)s0 * ystride + f0);
            FV v1 = *(const FV*)(Ya + (size_t)s1 * ystride + f0);
            FV v2 = *(const FV*)(Ya + (size_t)s2 * ystride + f0);
            FV v3 = *(const FV*)(Ya + (size_t)s3 * ystride + f0);
            float m1 = b1 ? 1.0f : 0.0f, m2 = b2 ? 1.0f : 0.0f, m3 = b3 ? 1.0f : 0.0f;
#pragma unroll
            for (int k = 0; k < VEC; ++k)
                accA[k] += (float)v0[k] + m1 * (float)v1[k]
                         + m2 * (float)v2[k] + m3 * (float)v3[k];
        }
    }
    {
        const int* rp = row_ptr + (size_t)gb * (N + 1);
        const int* cg = col + (size_t)gb * E;
        int beg = rp[i], end = rp[i + 1];
        for (int e = beg; e < end; e += 4) {
            int s0 = cg[e];
            bool b1 = e + 1 < end, b2 = e + 2 < end, b3 = e + 3 < end;
            int s1 = b1 ? cg[e + 1] : s0;
            int s2 = b2 ? cg[e + 2] : s0;
            int s3 = b3 ? cg[e + 3] : s0;
            FV v0 = *(const FV*)(Yb + (size_t)s0 * ystride + f0);
            FV v1 = *(const FV*)(Yb + (size_t)s1 * ystride + f0);
            FV v2 = *(const FV*)(Yb + (size_t)s2 * ystride + f0);
            FV v3 = *(const FV*)(Yb + (size_t)s3 * ystride + f0);
            float m1 = b1 ? 1.0f : 0.0f, m2 = b2 ? 1.0f : 0.0f, m3 = b3 ? 1.0f : 0.0f;
#pragma unroll
            for (int k = 0; k < VEC; ++k)
                accB[k] += (float)v0[k] + m1 * (float)v1[k]
                         + m2 * (float)v2[k] + m3 * (float)v3[k];
        }
    }
    float ria = rs_in[(size_t)ga * N + i];
    float rib = rs_in[(size_t)gb * N + i];
    FV o;
#pragma unroll
    for (int k = 0; k < VEC; ++k) {
        float v = ria * accA[k] + rib * accB[k]
                + ba0[side * F + f0 + k] + bb0[side * F + f0 + k];
        o[k] = (_Float16)fmaxf(v, 0.0f);
    }
    *(FV*)(outb + side * out_sidestride + (size_t)i * ostride + f0) = o;
}

__global__ __launch_bounds__(256) void k_agg256(const _Float16* Ya0, const _Float16* Yb0,
                                                int ystride, const int* row_ptr, const int* col,
                                                const float* rs_in, int ga0, int gb0,
                                                const float* ba0, const float* bb0,
                                                _Float16* outb, size_t oss, int ostride,
                                                int N, int E) {
    agg_body<f16x4, 4>(Ya0, Yb0, ystride, row_ptr, col, rs_in, ga0, gb0,
                       ba0, bb0, outb, oss, ostride, 256, N, E);
}

__global__ __launch_bounds__(256) void k_agg128(const _Float16* Ya0, const _Float16* Yb0,
                                                int ystride, const int* row_ptr, const int* col,
                                                const float* rs_in, int ga0, int gb0,
                                                const float* ba0, const float* bb0,
                                                _Float16* outb, size_t oss, int ostride,
                                                int N, int E) {
    agg_body<f16x2, 2>(Ya0, Yb0, ystride, row_ptr, col, rs_in, ga0, gb0,
                       ba0, bb0, outb, oss, ostride, 128, N, E);
}

// ------- w reduction: w[m] = sum_f tanh(T[m][f]+bp[f])*q[f] ---------------
__global__ __launch_bounds__(256) void k_wred(const _Float16* __restrict__ T,
                                              const float* __restrict__ bp,
                                              const float* __restrict__ q,
                                              float* __restrict__ w_all, int N) {
    int m = blockIdx.x * 4 + (threadIdx.x >> 6);
    int lane = threadIdx.x & 63;
    if (m >= 6 * N) return;
    f16x2 v2 = *(const f16x2*)(T + (size_t)m * 128 + 2 * lane);
    float v = tanhf((float)v2[0] + bp[2 * lane]) * q[2 * lane]
            + tanhf((float)v2[1] + bp[2 * lane + 1]) * q[2 * lane + 1];
#pragma unroll
    for (int o = 1; o < 64; o <<= 1) v += __shfl_xor(v, o);
    if (lane == 0) {
        int side = m / (3 * N);
        int rem = m - side * 3 * N;
        int node = rem / 3, k = rem - node * 3;
        w_all[((size_t)side * 3 + k) * N + node] = v;
    }
}

// ---------------- beta: deterministic reduce + softmax --------------------
__global__ __launch_bounds__(256) void k_beta(const float* __restrict__ w_all,
                                              float* __restrict__ beta_ws,
                                              float* __restrict__ beta_out, int N) {
    int side = blockIdx.x;
    int tid = threadIdx.x;
    __shared__ float red[256];
    float sums[3];
    for (int k = 0; k < 3; ++k) {
        float s = 0.0f;
        for (int i = tid; i < N; i += 256) s += w_all[((size_t)side * 3 + k) * N + i];
        red[tid] = s;
        __syncthreads();
        for (int off = 128; off > 0; off >>= 1) {
            if (tid < off) red[tid] += red[tid + off];
            __syncthreads();
        }
        sums[k] = red[0];
        __syncthreads();
    }
    if (tid == 0) {
        float inv = 1.0f / (float)N;
        float m0 = sums[0] * inv, m1 = sums[1] * inv, m2 = sums[2] * inv;
        float mx = fmaxf(m0, fmaxf(m1, m2));
        float e0 = expf(m0 - mx), e1 = expf(m1 - mx), e2 = expf(m2 - mx);
        float denom = e0 + e1 + e2;
        float b0 = e0 / denom, b1 = e1 / denom, b2 = e2 / denom;
        beta_ws[side * 3 + 0] = b0; beta_out[side * 3 + 0] = b0;
        beta_ws[side * 3 + 1] = b1; beta_out[side * 3 + 1] = b1;
        beta_ws[side * 3 + 2] = b2; beta_out[side * 3 + 2] = b2;
    }
}

// ---------------- emb = sum_k beta[k] * z[:,k,:] (f16x2) ------------------
__global__ __launch_bounds__(64) void k_emb(const _Float16* __restrict__ z,
                                            const float* __restrict__ beta_ws,
                                            float* __restrict__ out, int N) {
    int i = blockIdx.x, side = blockIdx.y, t = threadIdx.x;
    const _Float16* zr = z + (size_t)side * N * 384 + (size_t)i * 384;
    const float* b = beta_ws + side * 3;
    f16x2 z0 = *(const f16x2*)(zr + 2 * t);
    f16x2 z1 = *(const f16x2*)(zr + 128 + 2 * t);
    f16x2 z2 = *(const f16x2*)(zr + 256 + 2 * t);
    float2 o;
    o.x = b[0] * (float)z0[0] + b[1] * (float)z1[0] + b[2] * (float)z2[0];
    o.y = b[0] * (float)z0[1] + b[1] * (float)z1[1] + b[2] * (float)z2[1];
    *(float2*)&out[(size_t)side * N * 128 + (size_t)i * 128 + 2 * t] = o;
}

// ---------------------------------------------------------------------------
extern "C" void kernel_launch(void* const* d_in, const int* in_sizes, int n_in,
                              void* d_out, int out_size, void* d_ws, size_t ws_size,
                              hipStream_t stream) {
    const float* x_drug = (const float*)d_in[0];
    const float* x_pro  = (const float*)d_in[1];
    const int*   src    = (const int*)d_in[2];
    const int*   dst    = (const int*)d_in[3];
    const float* W1     = (const float*)d_in[4];
    const float* b1     = (const float*)d_in[5];
    const float* W2     = (const float*)d_in[6];
    const float* b2     = (const float*)d_in[7];
    const float* Wp     = (const float*)d_in[8];
    const float* bp     = (const float*)d_in[9];
    const float* q      = (const float*)d_in[10];
    float* out = (float*)d_out;

    const int N = in_sizes[0] / IN_F;      // 30000
    const int E = in_sizes[2] / 16;        // 250000

    size_t off = 0;
    auto alloc = [&](size_t bytes) -> void* {
        void* p = (char*)d_ws + off;
        off += (bytes + 255) & ~(size_t)255;
        return p;
    };
    int*      deg_in  = (int*)alloc((size_t)NG * N * 4);
    int*      row_ptr = (int*)alloc((size_t)NG * (N + 1) * 4);
    int*      col     = (int*)alloc((size_t)NG * E * 4);
    float*    rs_out  = (float*)alloc((size_t)NG * N * 4);
    float*    rs_in   = (float*)alloc((size_t)NG * N * 4);
    _Float16* xh      = (_Float16*)alloc((size_t)2 * N * IN_F * 2);          // [2][N][512]
    _Float16* W1cat   = (_Float16*)alloc((size_t)6 * 2 * HID_F * IN_F * 2);  // [6][512][512]
    _Float16* W2cat   = (_Float16*)alloc((size_t)6 * 2 * OUT_F * HID_F * 2); // [6][256][256]
    _Float16* WpT     = (_Float16*)alloc((size_t)128 * 128 * 2);
    _Float16* Y1      = (_Float16*)alloc((size_t)2 * N * 512 * 2);           // [2][N][512]
    _Float16* Y2      = (_Float16*)alloc((size_t)2 * N * 256 * 2);           // [2][N][256]
    _Float16* H1      = (_Float16*)alloc((size_t)2 * N * HID_F * 2);         // [2][N][256]
    _Float16* zbuf    = (_Float16*)alloc((size_t)2 * N * 384 * 2);           // [2][N][384]
    float*    w_all   = (float*)alloc((size_t)2 * 3 * N * 4);
    float*    beta_ws = (float*)alloc(64);
    // Overlays into Y1 (61.4 MB): hist slices (23 MB, dead before first GEMM)
    // and attention T (46 MB, after hists are dead).
    int*      hin  = (int*)Y1;                       // [NG][ES][N]
    int*      hout = hin + (size_t)NG * ES * N;      // [NG][ES][N]
    _Float16* T    = Y1;
    (void)ws_size; (void)n_in; (void)out_size;

    // ---- CSR build (edge-sliced, atomic-free hist) ----
    dim3 hg(NG, NPART, ES);
    k_hist<<<hg, 512, 0, stream>>>(src, dst, hin, hout, N, E);
    k_rs2<<<(NG * N + 255) / 256, 256, 0, stream>>>(hin, hout, deg_in, rs_out, rs_in, N);
    k_scan<<<NG, 1024, 0, stream>>>(deg_in, row_ptr, N);
    k_fill3<<<hg, 512, 0, stream>>>(src, dst, row_ptr, hin, col, N, E);

    // ---- fp16 conversions ----
    size_t nx = (size_t)N * IN_F;
    k_cvt16<<<(int)((nx / 8 + 255) / 256), 256, 0, stream>>>(x_drug, xh, nx);
    k_cvt16<<<(int)((nx / 8 + 255) / 256), 256, 0, stream>>>(x_pro,  xh + nx, nx);
    k_cvtT<<<dim3(IN_F / 32, HID_F / 32, NG), 256, 0, stream>>>(W1, W1cat, IN_F, HID_F);
    k_cvtT<<<dim3(HID_F / 32, OUT_F / 32, NG), 256, 0, stream>>>(W2, W2cat, HID_F, OUT_F);
    k_cvtWp<<<dim3(4, 4), 256, 0, stream>>>(Wp, WpT);

    dim3 g1(512 / 128, (N + 127) / 128, 2);   // layer-1 GEMM: K=512, Nn=512, z=2
    dim3 g2(256 / 128, (N + 127) / 128, 2);   // layer-2 GEMM: K=256, Nn=256, z=2
    dim3 agrid((N + 3) / 4, 2);
    dim3 egrid(N, 2);

    for (int ci = 0; ci < 3; ++ci) {
        int c = chan_of(ci);
        // layer 1: z=0: xh_d @ [W1 c r0 | W1 c r1]; z=1: xh_p @ [W1 c r2 | W1 c r3]
        // epilogue scales row by rs_out[g], g = ci*4 + 2z (+1 for col>=256)
        k_gemm16<<<g1, 256, 0, stream>>>(xh, (size_t)N * IN_F,
                                         W1cat + (size_t)ci * 2 * 512 * 512, (size_t)512 * 512,
                                         Y1, (size_t)N * 512,
                                         rs_out + (size_t)ci * 4 * N, N, 256,
                                         N, IN_F, 512);
        // L1 agg -> H1[side][N][256]
        k_agg256<<<agrid, 256, 0, stream>>>(Y1, Y1 + (size_t)N * 512, 512,
                                            row_ptr, col, rs_in,
                                            ci * 4 + 0, ci * 4 + 2,
                                            b1 + (size_t)c * 4 * HID_F, b1 + (size_t)(c * 4 + 2) * HID_F,
                                            H1, (size_t)N * HID_F, HID_F, N, E);
        // layer 2: z=0: H1d @ [W2 c r0 | W2 c r1]; z=1: H1p @ [W2 c r2 | W2 c r3]
        k_gemm16<<<g2, 256, 0, stream>>>(H1, (size_t)N * HID_F,
                                         W2cat + (size_t)ci * 2 * 256 * 256, (size_t)256 * 256,
                                         Y2, (size_t)N * 256,
                                         rs_out + (size_t)ci * 4 * N, N, 128,
                                         N, HID_F, 256);
        // L2 agg -> z[side][N][384] col block ci*128
        k_agg128<<<agrid, 256, 0, stream>>>(Y2, Y2 + (size_t)N * 256, 256,
                                            row_ptr, col, rs_in,
                                            ci * 4 + 0, ci * 4 + 2,
                                            b2 + (size_t)c * 4 * OUT_F, b2 + (size_t)(c * 4 + 2) * OUT_F,
                                            zbuf + (size_t)ci * OUT_F, (size_t)N * 384, 384, N, E);
    }

    // ---- semantic attention: T = zbuf_flat[2N*3,128] @ WpT, then reduce ----
    int Mrows = 2 * N * 3;
    dim3 gT(1, (Mrows + 127) / 128, 1);
    k_gemm16<<<gT, 256, 0, stream>>>(zbuf, 0, WpT, 0, T, 0,
                                     nullptr, 0, 0, Mrows, 128, 128);
    k_wred<<<(Mrows + 3) / 4, 256, 0, stream>>>(T, bp, q, w_all, N);
    k_beta<<<2, 256, 0, stream>>>(w_all, beta_ws, out + (size_t)2 * N * OUT_F, N);
    k_emb<<<egrid, 64, 0, stream>>>(zbuf, beta_ws, out, N);
}

// Round 8
// 1116.016 us; speedup vs baseline: 3.4280x; 1.0892x over previous
//
#include <hip/hip_runtime.h>
#include <math.h>

// ---------------------------------------------------------------------------
// MCKRL round 8: k_beta was top dispatch (88us, 2 blocks, latency chain) ->
// two-stage deterministic reduction (~8us). Gather edge loop unrolled 8-deep
// (more MLP). cvt16 merged to one launch; k_emb re-blocked. Rest as round 7.
// ---------------------------------------------------------------------------

#define IN_F  512
#define HID_F 256
#define OUT_F 128
#define NG    12       // 3 live channels x 4 relations
#define NPART 16
#define RANGE 1875     // 16*1875 = 30000
#define ES    8        // edge slices
#define BCH   32       // beta stage-1 chunks per (side,k)

typedef _Float16 f16x2 __attribute__((ext_vector_type(2)));
typedef _Float16 f16x4 __attribute__((ext_vector_type(4)));
typedef _Float16 f16x8 __attribute__((ext_vector_type(8)));
typedef float    f32x4 __attribute__((ext_vector_type(4)));

#define AS1 __attribute__((address_space(1)))
#define AS3 __attribute__((address_space(3)))

__device__ __forceinline__ void gld16(const void* g, void* l) {
    __builtin_amdgcn_global_load_lds((const AS1 void*)g, (AS3 void*)l, 16, 0, 0);
}

__host__ __device__ __forceinline__ int chan_of(int ci) { return ci == 0 ? 0 : ci + 1; } // {0,2,3}

// ------- edge-sliced histograms: h[g][es][node], atomic-free global writes --
__global__ __launch_bounds__(512) void k_hist(const int* __restrict__ src,
                                              const int* __restrict__ dst,
                                              int* __restrict__ hin,
                                              int* __restrict__ hout,
                                              int N, int E) {
    __shared__ int hi[RANGE], ho[RANGE];
    int g = blockIdx.x, p = blockIdx.y, es = blockIdx.z, t = threadIdx.x;
    for (int i = t; i < RANGE; i += 512) { hi[i] = 0; ho[i] = 0; }
    __syncthreads();
    int ci = g >> 2, c = chan_of(ci), r = g & 3;
    const int* sp = src + (size_t)(c * 4 + r) * E;
    const int* dp = dst + (size_t)(c * 4 + r) * E;
    int lo = p * RANGE;
    int sl = E / ES;
    int e0 = es * sl, e1 = (es == ES - 1) ? E : e0 + sl;
    for (int e = e0 + t; e < e1; e += 512) {
        int s = sp[e] - lo;
        int d = dp[e] - lo;
        if ((unsigned)s < (unsigned)RANGE) atomicAdd(&ho[s], 1);
        if ((unsigned)d < (unsigned)RANGE) atomicAdd(&hi[d], 1);
    }
    __syncthreads();
    int* hing  = hin  + ((size_t)g * ES + es) * N;
    int* houtg = hout + ((size_t)g * ES + es) * N;
    for (int i = t; i < RANGE; i += 512) {
        int node = lo + i;
        if (node < N) { hing[node] = hi[i]; houtg[node] = ho[i]; }
    }
}

// ------- sum slices -> deg_in, rs_out, rs_in ------------------------------
__global__ void k_rs2(const int* __restrict__ hin, const int* __restrict__ hout,
                      int* __restrict__ deg_in,
                      float* __restrict__ rs_out, float* __restrict__ rs_in, int N) {
    int i = blockIdx.x * 256 + threadIdx.x;
    if (i >= NG * N) return;
    int g = i / N, n = i - g * N;
    int di = 0, dq = 0;
#pragma unroll
    for (int es = 0; es < ES; ++es) {
        di += hin [((size_t)g * ES + es) * N + n];
        dq += hout[((size_t)g * ES + es) * N + n];
    }
    deg_in[i] = di;
    rs_in[i]  = rsqrtf(fmaxf((float)di, 1.0f));
    rs_out[i] = rsqrtf(fmaxf((float)dq, 1.0f));
}

// ---------------- exclusive scan of deg_in -> row_ptr (shuffle) -----------
__global__ __launch_bounds__(1024) void k_scan(const int* __restrict__ deg_in,
                                               int* __restrict__ row_ptr, int N) {
    int g = blockIdx.x;
    const int* dg = deg_in + (size_t)g * N;
    int* rp = row_ptr + (size_t)g * (N + 1);
    __shared__ int wsum[16];
    int tid = threadIdx.x;
    int lane = tid & 63, wv = tid >> 6;
    int run = 0;
    for (int basei = 0; basei < N; basei += 1024) {
        int i = basei + tid;
        int v = (i < N) ? dg[i] : 0;
        int x = v;
#pragma unroll
        for (int off = 1; off < 64; off <<= 1) {
            int y = __shfl_up(x, off);
            if (lane >= off) x += y;
        }
        if (lane == 63) wsum[wv] = x;
        __syncthreads();
        if (wv == 0) {
            int s = (lane < 16) ? wsum[lane] : 0;
#pragma unroll
            for (int off = 1; off < 16; off <<= 1) {
                int y = __shfl_up(s, off);
                if (lane >= off) s += y;
            }
            if (lane < 16) wsum[lane] = s;
        }
        __syncthreads();
        int woff = wv ? wsum[wv - 1] : 0;
        if (i < N) rp[i] = run + woff + x - v;
        run += wsum[15];
        __syncthreads();
    }
    if (tid == 0) rp[N] = run;
}

// ------- CSR fill: edge-sliced, LDS cursors from row_ptr + slice prefix ---
__global__ __launch_bounds__(512) void k_fill3(const int* __restrict__ src,
                                               const int* __restrict__ dst,
                                               const int* __restrict__ row_ptr,
                                               const int* __restrict__ hin,
                                               int* __restrict__ col, int N, int E) {
    __shared__ int cur[RANGE];
    int g = blockIdx.x, p = blockIdx.y, es = blockIdx.z, t = threadIdx.x;
    int lo = p * RANGE;
    const int* rp = row_ptr + (size_t)g * (N + 1);
    for (int i = t; i < RANGE; i += 512) {
        int node = lo + i;
        int base = 0;
        if (node < N) {
            base = rp[node];
            for (int e2 = 0; e2 < es; ++e2)
                base += hin[((size_t)g * ES + e2) * N + node];
        }
        cur[i] = base;
    }
    __syncthreads();
    int ci = g >> 2, c = chan_of(ci), r = g & 3;
    const int* sp = src + (size_t)(c * 4 + r) * E;
    const int* dp = dst + (size_t)(c * 4 + r) * E;
    int* cg = col + (size_t)g * E;
    int sl = E / ES;
    int e0 = es * sl, e1 = (es == ES - 1) ? E : e0 + sl;
    for (int e = e0 + t; e < e1; e += 512) {
        int s = sp[e];
        int d = dp[e] - lo;
        if ((unsigned)d < (unsigned)RANGE) {
            int pos = atomicAdd(&cur[d], 1);
            cg[pos] = s;
        }
    }
}

// ------- fp32 -> fp16, two sources (side = blockIdx.y), n mult of 8 -------
__global__ void k_cvt16b(const float* __restrict__ inA, const float* __restrict__ inB,
                         _Float16* __restrict__ out, size_t n) {
    size_t i = ((size_t)blockIdx.x * 256 + threadIdx.x) * 8;
    if (i >= n) return;
    const float* in = blockIdx.y ? inB : inA;
    float4 a = *(const float4*)(in + i);
    float4 b = *(const float4*)(in + i + 4);
    f16x8 v;
    v[0] = (_Float16)a.x; v[1] = (_Float16)a.y; v[2] = (_Float16)a.z; v[3] = (_Float16)a.w;
    v[4] = (_Float16)b.x; v[5] = (_Float16)b.y; v[6] = (_Float16)b.z; v[7] = (_Float16)b.w;
    *(f16x8*)(out + blockIdx.y * n + i) = v;
}

// ------- weight transpose+convert into concatenated f16 layout ------------
__global__ __launch_bounds__(256) void k_cvtT(const float* __restrict__ W,
                                              _Float16* __restrict__ out,
                                              int K, int Nn) {
    __shared__ float tile[32][33];
    int gi = blockIdx.z, ci = gi >> 2, c = chan_of(ci), r = gi & 3;
    const float* Wg = W + (size_t)(c * 4 + r) * K * Nn;
    _Float16* Wo = out + ((size_t)(ci * 2 + (r >> 1)) * 2 * Nn + (size_t)(r & 1) * Nn) * K;
    int k0 = blockIdx.x * 32, n0 = blockIdx.y * 32;
    int tx = threadIdx.x & 31, ty = threadIdx.x >> 5;   // 32 x 8
    for (int yy = ty; yy < 32; yy += 8)
        tile[yy][tx] = Wg[(size_t)(k0 + yy) * Nn + n0 + tx];
    __syncthreads();
    for (int yy = ty; yy < 32; yy += 8)
        Wo[(size_t)(n0 + yy) * K + k0 + tx] = (_Float16)tile[tx][yy];
}

// ------- Wp [128][128] f32 -> WpT [n][k] f16 ------------------------------
__global__ __launch_bounds__(256) void k_cvtWp(const float* __restrict__ Wp,
                                               _Float16* __restrict__ WpT) {
    __shared__ float tile[32][33];
    int k0 = blockIdx.x * 32, n0 = blockIdx.y * 32;
    int tx = threadIdx.x & 31, ty = threadIdx.x >> 5;
    for (int yy = ty; yy < 32; yy += 8)
        tile[yy][tx] = Wp[(size_t)(k0 + yy) * 128 + n0 + tx];
    __syncthreads();
    for (int yy = ty; yy < 32; yy += 8)
        WpT[(size_t)(n0 + yy) * 128 + k0 + tx] = (_Float16)tile[tx][yy];
}

// ---------------- z-batched fp16 MFMA GEMM: C = A @ Bt^T ------------------
// 128x128 tile, BK=64, 256 threads (4 waves 2x2), 16x16x32_f16 MFMA.
// Epilogue folds per-source-row rs_out scaling (col-half-dependent).
__global__ __launch_bounds__(256) void k_gemm16(const _Float16* __restrict__ A0, size_t Azs,
                                                const _Float16* __restrict__ B0, size_t Bzs,
                                                _Float16* __restrict__ C0, size_t Czs,
                                                const float* __restrict__ rs0, int rsN,
                                                int Nsplit,
                                                int M, int K, int Nn) {
    const _Float16* A = A0 + (size_t)blockIdx.z * Azs;
    const _Float16* Bt = B0 + (size_t)blockIdx.z * Bzs;
    _Float16* C = C0 + (size_t)blockIdx.z * Czs;
    const float* rsA = rs0 ? rs0 + (size_t)(2 * blockIdx.z) * rsN : nullptr;
    __shared__ __align__(16) _Float16 As[128 * 64];
    __shared__ __align__(16) _Float16 Bs[128 * 64];
    int t = threadIdx.x;
    int lane = t & 63, wid = t >> 6;
    int wm = wid >> 1, wn = wid & 1;
    int brow = blockIdx.y * 128, bcol = blockIdx.x * 128;

    f32x4 acc[4][4] = {};
    int mrow = lane & 15;
    int khalf = lane >> 4;   // 0..3

    for (int k0 = 0; k0 < K; k0 += 64) {
        __syncthreads();
#pragma unroll
        for (int i = 0; i < 4; ++i) {
            int L = t + i * 256;
            int row = L >> 3, spp = L & 7;
            int sg = spp ^ (row & 7);           // pre-swizzled global slot
            int ra = brow + row; if (ra > M - 1) ra = M - 1;
            gld16((const void*)(A + (size_t)ra * K + (size_t)(k0 + sg * 8)),
                  (void*)(As + (size_t)(i * 256 + wid * 64) * 8));
            int rb = bcol + row;
            gld16((const void*)(Bt + (size_t)rb * K + (size_t)(k0 + sg * 8)),
                  (void*)(Bs + (size_t)(i * 256 + wid * 64) * 8));
        }
        __syncthreads();
#pragma unroll
        for (int ks = 0; ks < 2; ++ks) {
            f16x8 af[4], bf[4];
#pragma unroll
            for (int mi = 0; mi < 4; ++mi) {
                int r = wm * 64 + mi * 16 + mrow;
                int s = ks * 4 + khalf;
                int ph = s ^ (r & 7);
                af[mi] = *(const f16x8*)(As + r * 64 + ph * 8);
            }
#pragma unroll
            for (int ni = 0; ni < 4; ++ni) {
                int r = wn * 64 + ni * 16 + mrow;
                int s = ks * 4 + khalf;
                int ph = s ^ (r & 7);
                bf[ni] = *(const f16x8*)(Bs + r * 64 + ph * 8);
            }
#pragma unroll
            for (int mi = 0; mi < 4; ++mi)
#pragma unroll
                for (int ni = 0; ni < 4; ++ni)
                    acc[mi][ni] = __builtin_amdgcn_mfma_f32_16x16x32_f16(
                        af[mi], bf[ni], acc[mi][ni], 0, 0, 0);
        }
    }
#pragma unroll
    for (int mi = 0; mi < 4; ++mi) {
#pragma unroll
        for (int r = 0; r < 4; ++r) {
            int row = brow + wm * 64 + mi * 16 + (lane >> 4) * 4 + r;
            if (row < M) {
                float sA = 1.0f, sB = 1.0f;
                if (rsA) { sA = rsA[row]; sB = rsA[rsN + row]; }
#pragma unroll
                for (int ni = 0; ni < 4; ++ni) {
                    int colx = bcol + wn * 64 + ni * 16 + (lane & 15);
                    float sc = (colx < Nsplit) ? sA : sB;
                    C[(size_t)row * Nn + colx] = (_Float16)(acc[mi][ni][r] * sc);
                }
            }
        }
    }
}

// ------- gather: one wave per node, 8-deep unrolled edge loop -------------
// Y rows already rs_out-scaled (GEMM epilogue). VEC = F/64 halves per lane.
template<typename FV, int VEC>
__device__ __forceinline__ void agg_body(const _Float16* __restrict__ Ya0,
                                         const _Float16* __restrict__ Yb0, int ystride,
                                         const int* __restrict__ row_ptr,
                                         const int* __restrict__ col,
                                         const float* __restrict__ rs_in,
                                         int ga0, int gb0,
                                         const float* __restrict__ ba0,
                                         const float* __restrict__ bb0,
                                         _Float16* __restrict__ outb,
                                         size_t out_sidestride, int ostride,
                                         int F, int N, int E) {
    int wv = threadIdx.x >> 6, lane = threadIdx.x & 63;
    int i = blockIdx.x * 4 + wv;
    if (i >= N) return;
    int side = blockIdx.y;
    int f0 = VEC * lane;
    const _Float16* Ybase[2] = { Ya0 + side * F, Yb0 + side * F };
    int gg[2] = { ga0 + side, gb0 + side };

    float accT[2][VEC] = {};
#pragma unroll
    for (int h = 0; h < 2; ++h) {
        const int* rp = row_ptr + (size_t)gg[h] * (N + 1);
        const int* cg = col + (size_t)gg[h] * E;
        const _Float16* Y = Ybase[h];
        int beg = rp[i], end = rp[i + 1];
        for (int e = beg; e < end; e += 8) {
            int idx[8]; float m[8]; FV v[8];
            idx[0] = cg[e]; m[0] = 1.0f;
#pragma unroll
            for (int u = 1; u < 8; ++u) {
                bool ok = (e + u < end);
                idx[u] = ok ? cg[e + u] : idx[0];
                m[u] = ok ? 1.0f : 0.0f;
            }
#pragma unroll
            for (int u = 0; u < 8; ++u)
                v[u] = *(const FV*)(Y + (size_t)idx[u] * ystride + f0);
#pragma unroll
            for (int u = 0; u < 8; ++u)
#pragma unroll
                for (int k = 0; k < VEC; ++k)
                    accT[h][k] = fmaf(m[u], (float)v[u][k], accT[h][k]);
        }
    }
    float ria = rs_in[(size_t)gg[0] * N + i];
    float rib = rs_in[(size_t)gg[1] * N + i];
    FV o;
#pragma unroll
    for (int k = 0; k < VEC; ++k) {
        float v = ria * accT[0][k] + rib * accT[1][k]
                + ba0[side * F + f0 + k] + bb0[side * F + f0 + k];
        o[k] = (_Float16)fmaxf(v, 0.0f);
    }
    *(FV*)(outb + side * out_sidestride + (size_t)i * ostride + f0) = o;
}

__global__ __launch_bounds__(256) void k_agg256(const _Float16* Ya0, const _Float16* Yb0,
                                                int ystride, const int* row_ptr, const int* col,
                                                const float* rs_in, int ga0, int gb0,
                                                const float* ba0, const float* bb0,
                                                _Float16* outb, size_t oss, int ostride,
                                                int N, int E) {
    agg_body<f16x4, 4>(Ya0, Yb0, ystride, row_ptr, col, rs_in, ga0, gb0,
                       ba0, bb0, outb, oss, ostride, 256, N, E);
}

__global__ __launch_bounds__(256) void k_agg128(const _Float16* Ya0, const _Float16* Yb0,
                                                int ystride, const int* row_ptr, const int* col,
                                                const float* rs_in, int ga0, int gb0,
                                                const float* ba0, const float* bb0,
                                                _Float16* outb, size_t oss, int ostride,
                                                int N, int E) {
    agg_body<f16x2, 2>(Ya0, Yb0, ystride, row_ptr, col, rs_in, ga0, gb0,
                       ba0, bb0, outb, oss, ostride, 128, N, E);
}

// ------- w reduction: w[m] = sum_f tanh(T[m][f]+bp[f])*q[f] ---------------
__global__ __launch_bounds__(256) void k_wred(const _Float16* __restrict__ T,
                                              const float* __restrict__ bp,
                                              const float* __restrict__ q,
                                              float* __restrict__ w_all, int N) {
    int m = blockIdx.x * 4 + (threadIdx.x >> 6);
    int lane = threadIdx.x & 63;
    if (m >= 6 * N) return;
    f16x2 v2 = *(const f16x2*)(T + (size_t)m * 128 + 2 * lane);
    float v = tanhf((float)v2[0] + bp[2 * lane]) * q[2 * lane]
            + tanhf((float)v2[1] + bp[2 * lane + 1]) * q[2 * lane + 1];
#pragma unroll
    for (int o = 1; o < 64; o <<= 1) v += __shfl_xor(v, o);
    if (lane == 0) {
        int side = m / (3 * N);
        int rem = m - side * 3 * N;
        int node = rem / 3, k = rem - node * 3;
        w_all[((size_t)side * 3 + k) * N + node] = v;
    }
}

// ------- beta stage 1: partial sums, grid (BCH, 3, 2) ---------------------
__global__ __launch_bounds__(256) void k_beta1(const float* __restrict__ w_all,
                                               float* __restrict__ partials, int N) {
    int chunk = blockIdx.x, k = blockIdx.y, side = blockIdx.z;
    const float* w = w_all + ((size_t)side * 3 + k) * N;
    int per = (N + BCH - 1) / BCH;
    int i0 = chunk * per;
    int i1 = i0 + per; if (i1 > N) i1 = N;
    int tid = threadIdx.x;
    float s = 0.0f;
    for (int i = i0 + tid; i < i1; i += 256) s += w[i];
    __shared__ float red[256];
    red[tid] = s;
    __syncthreads();
    for (int off = 128; off > 0; off >>= 1) {
        if (tid < off) red[tid] += red[tid + off];
        __syncthreads();
    }
    if (tid == 0) partials[((size_t)side * 3 + k) * BCH + chunk] = red[0];
}

// ------- beta stage 2: final sums + softmax + write -----------------------
__global__ __launch_bounds__(64) void k_beta2(const float* __restrict__ partials,
                                              float* __restrict__ beta_ws,
                                              float* __restrict__ beta_out, int N) {
    __shared__ float sums[6];
    int tid = threadIdx.x;
    if (tid < 6) {
        float s = 0.0f;
        for (int j = 0; j < BCH; ++j) s += partials[(size_t)tid * BCH + j];
        sums[tid] = s;
    }
    __syncthreads();
    if (tid < 2) {
        int side = tid;
        float inv = 1.0f / (float)N;
        float m0 = sums[side * 3 + 0] * inv;
        float m1 = sums[side * 3 + 1] * inv;
        float m2 = sums[side * 3 + 2] * inv;
        float mx = fmaxf(m0, fmaxf(m1, m2));
        float e0 = expf(m0 - mx), e1 = expf(m1 - mx), e2 = expf(m2 - mx);
        float denom = e0 + e1 + e2;
        float b0 = e0 / denom, b1 = e1 / denom, b2 = e2 / denom;
        beta_ws[side * 3 + 0] = b0; beta_out[side * 3 + 0] = b0;
        beta_ws[side * 3 + 1] = b1; beta_out[side * 3 + 1] = b1;
        beta_ws[side * 3 + 2] = b2; beta_out[side * 3 + 2] = b2;
    }
}

// ---------------- emb = sum_k beta[k] * z[:,k,:] (f16x2, 4 nodes/block) ---
__global__ __launch_bounds__(256) void k_emb(const _Float16* __restrict__ z,
                                             const float* __restrict__ beta_ws,
                                             float* __restrict__ out, int N) {
    int i = blockIdx.x * 4 + (threadIdx.x >> 6);
    if (i >= N) return;
    int side = blockIdx.y, t = threadIdx.x & 63;
    const _Float16* zr = z + (size_t)side * N * 384 + (size_t)i * 384;
    const float* b = beta_ws + side * 3;
    f16x2 z0 = *(const f16x2*)(zr + 2 * t);
    f16x2 z1 = *(const f16x2*)(zr + 128 + 2 * t);
    f16x2 z2 = *(const f16x2*)(zr + 256 + 2 * t);
    float2 o;
    o.x = b[0] * (float)z0[0] + b[1] * (float)z1[0] + b[2] * (float)z2[0];
    o.y = b[0] * (float)z0[1] + b[1] * (float)z1[1] + b[2] * (float)z2[1];
    *(float2*)&out[(size_t)side * N * 128 + (size_t)i * 128 + 2 * t] = o;
}

// ---------------------------------------------------------------------------
extern "C" void kernel_launch(void* const* d_in, const int* in_sizes, int n_in,
                              void* d_out, int out_size, void* d_ws, size_t ws_size,
                              hipStream_t stream) {
    const float* x_drug = (const float*)d_in[0];
    const float* x_pro  = (const float*)d_in[1];
    const int*   src    = (const int*)d_in[2];
    const int*   dst    = (const int*)d_in[3];
    const float* W1     = (const float*)d_in[4];
    const float* b1     = (const float*)d_in[5];
    const float* W2     = (const float*)d_in[6];
    const float* b2     = (const float*)d_in[7];
    const float* Wp     = (const float*)d_in[8];
    const float* bp     = (const float*)d_in[9];
    const float* q      = (const float*)d_in[10];
    float* out = (float*)d_out;

    const int N = in_sizes[0] / IN_F;      // 30000
    const int E = in_sizes[2] / 16;        // 250000

    size_t off = 0;
    auto alloc = [&](size_t bytes) -> void* {
        void* p = (char*)d_ws + off;
        off += (bytes + 255) & ~(size_t)255;
        return p;
    };
    int*      deg_in  = (int*)alloc((size_t)NG * N * 4);
    int*      row_ptr = (int*)alloc((size_t)NG * (N + 1) * 4);
    int*      col     = (int*)alloc((size_t)NG * E * 4);
    float*    rs_out  = (float*)alloc((size_t)NG * N * 4);
    float*    rs_in   = (float*)alloc((size_t)NG * N * 4);
    _Float16* xh      = (_Float16*)alloc((size_t)2 * N * IN_F * 2);          // [2][N][512]
    _Float16* W1cat   = (_Float16*)alloc((size_t)6 * 2 * HID_F * IN_F * 2);  // [6][512][512]
    _Float16* W2cat   = (_Float16*)alloc((size_t)6 * 2 * OUT_F * HID_F * 2); // [6][256][256]
    _Float16* WpT     = (_Float16*)alloc((size_t)128 * 128 * 2);
    _Float16* Y1      = (_Float16*)alloc((size_t)2 * N * 512 * 2);           // [2][N][512]
    _Float16* Y2      = (_Float16*)alloc((size_t)2 * N * 256 * 2);           // [2][N][256]
    _Float16* H1      = (_Float16*)alloc((size_t)2 * N * HID_F * 2);         // [2][N][256]
    _Float16* zbuf    = (_Float16*)alloc((size_t)2 * N * 384 * 2);           // [2][N][384]
    float*    w_all   = (float*)alloc((size_t)2 * 3 * N * 4);
    float*    partials= (float*)alloc((size_t)6 * BCH * 4);
    float*    beta_ws = (float*)alloc(64);
    // Overlays into Y1 (61.4 MB): hist slices (23 MB, dead before first GEMM)
    // and attention T (46 MB, after hists are dead).
    int*      hin  = (int*)Y1;                       // [NG][ES][N]
    int*      hout = hin + (size_t)NG * ES * N;      // [NG][ES][N]
    _Float16* T    = Y1;
    (void)ws_size; (void)n_in; (void)out_size;

    // ---- CSR build (edge-sliced, atomic-free hist) ----
    dim3 hg(NG, NPART, ES);
    k_hist<<<hg, 512, 0, stream>>>(src, dst, hin, hout, N, E);
    k_rs2<<<(NG * N + 255) / 256, 256, 0, stream>>>(hin, hout, deg_in, rs_out, rs_in, N);
    k_scan<<<NG, 1024, 0, stream>>>(deg_in, row_ptr, N);
    k_fill3<<<hg, 512, 0, stream>>>(src, dst, row_ptr, hin, col, N, E);

    // ---- fp16 conversions ----
    size_t nx = (size_t)N * IN_F;
    k_cvt16b<<<dim3((int)((nx / 8 + 255) / 256), 2), 256, 0, stream>>>(x_drug, x_pro, xh, nx);
    k_cvtT<<<dim3(IN_F / 32, HID_F / 32, NG), 256, 0, stream>>>(W1, W1cat, IN_F, HID_F);
    k_cvtT<<<dim3(HID_F / 32, OUT_F / 32, NG), 256, 0, stream>>>(W2, W2cat, HID_F, OUT_F);
    k_cvtWp<<<dim3(4, 4), 256, 0, stream>>>(Wp, WpT);

    dim3 g1(512 / 128, (N + 127) / 128, 2);   // layer-1 GEMM: K=512, Nn=512, z=2
    dim3 g2(256 / 128, (N + 127) / 128, 2);   // layer-2 GEMM: K=256, Nn=256, z=2
    dim3 agrid((N + 3) / 4, 2);

    for (int ci = 0; ci < 3; ++ci) {
        int c = chan_of(ci);
        // layer 1: z=0: xh_d @ [W1 c r0 | W1 c r1]; z=1: xh_p @ [W1 c r2 | W1 c r3]
        // epilogue scales row by rs_out[g], g = ci*4 + 2z (+1 for col>=256)
        k_gemm16<<<g1, 256, 0, stream>>>(xh, (size_t)N * IN_F,
                                         W1cat + (size_t)ci * 2 * 512 * 512, (size_t)512 * 512,
                                         Y1, (size_t)N * 512,
                                         rs_out + (size_t)ci * 4 * N, N, 256,
                                         N, IN_F, 512);
        // L1 agg -> H1[side][N][256]
        k_agg256<<<agrid, 256, 0, stream>>>(Y1, Y1 + (size_t)N * 512, 512,
                                            row_ptr, col, rs_in,
                                            ci * 4 + 0, ci * 4 + 2,
                                            b1 + (size_t)c * 4 * HID_F, b1 + (size_t)(c * 4 + 2) * HID_F,
                                            H1, (size_t)N * HID_F, HID_F, N, E);
        // layer 2: z=0: H1d @ [W2 c r0 | W2 c r1]; z=1: H1p @ [W2 c r2 | W2 c r3]
        k_gemm16<<<g2, 256, 0, stream>>>(H1, (size_t)N * HID_F,
                                         W2cat + (size_t)ci * 2 * 256 * 256, (size_t)256 * 256,
                                         Y2, (size_t)N * 256,
                                         rs_out + (size_t)ci * 4 * N, N, 128,
                                         N, HID_F, 256);
        // L2 agg -> z[side][N][384] col block ci*128
        k_agg128<<<agrid, 256, 0, stream>>>(Y2, Y2 + (size_t)N * 256, 256,
                                            row_ptr, col, rs_in,
                                            ci * 4 + 0, ci * 4 + 2,
                                            b2 + (size_t)c * 4 * OUT_F, b2 + (size_t)(c * 4 + 2) * OUT_F,
                                            zbuf + (size_t)ci * OUT_F, (size_t)N * 384, 384, N, E);
    }

    // ---- semantic attention: T = zbuf_flat[2N*3,128] @ WpT, then reduce ----
    int Mrows = 2 * N * 3;
    dim3 gT(1, (Mrows + 127) / 128, 1);
    k_gemm16<<<gT, 256, 0, stream>>>(zbuf, 0, WpT, 0, T, 0,
                                     nullptr, 0, 0, Mrows, 128, 128);
    k_wred<<<(Mrows + 3) / 4, 256, 0, stream>>>(T, bp, q, w_all, N);
    k_beta1<<<dim3(BCH, 3, 2), 256, 0, stream>>>(w_all, partials, N);
    k_beta2<<<1, 64, 0, stream>>>(partials, beta_ws, out + (size_t)2 * N * OUT_F, N);
    k_emb<<<agrid, 256, 0, stream>>>(zbuf, beta_ws, out, N);
}